// Round 11
// baseline (768.760 us; speedup 1.0000x reference)
//
#include <hip/hip_runtime.h>
#include <hip/hip_bf16.h>
#include <cstdint>
#include <math.h>

#define DEV static __device__ __forceinline__

typedef __attribute__((ext_vector_type(8))) __bf16 bf16x8v;
typedef __attribute__((ext_vector_type(4))) float f32x4;

constexpr int B = 4, T = 512, BT = B * T;
constexpr int D_MODEL = 769, D_INNER = 1538, D2 = 3076;
constexpr int DT_RANK = 49, D_STATE = 64;
constexpr int NLAYER = 2;
constexpr int DG8 = (D_INNER + 7) / 8;     // 193 d-groups of 8 for fused scan
// padded GEMM dims (K multiple of 64, N multiple of 128)
constexpr int KP_MODEL = 832;   // 769
constexpr int KP_INNER = 1600;  // 1538
constexpr int KP_DT    = 64;    // 49
constexpr int NP_IN  = 3200;    // 3076
constexpr int NP_X   = 256;     // 177
constexpr int NP_DT  = 1664;    // 1538
constexpr int NP_OUT = 896;     // 769
constexpr int KCONV  = 3456;    // 27*128 unified front-conv reduction
constexpr int NCONV  = 768;

DEV float siluf(float v) { return v / (1.f + __expf(-v)); }
DEV float fexp2(float x) { return __builtin_amdgcn_exp2f(x); }   // raw v_exp_f32

DEV float wredx(float v) {
#pragma unroll
  for (int o = 1; o < 64; o <<= 1) v += __shfl_xor(v, o);
  return v;
}

// DPP / swizzle cross-lane helpers (VALU-pipe DPP where possible)
#define DPPF(v, ctrl) __uint_as_float((uint)__builtin_amdgcn_mov_dpp((int)__float_as_uint(v), (ctrl), 0xf, 0xf, true))
#define SWZF(v, pat) __uint_as_float((uint)__builtin_amdgcn_ds_swizzle((int)__float_as_uint(v), (pat)))

DEV void gload_lds16(const void* g, void* l) {
  __builtin_amdgcn_global_load_lds(
      (const __attribute__((address_space(1))) uint32_t*)(uintptr_t)g,
      (__attribute__((address_space(3))) uint32_t*)(uint32_t)(uintptr_t)l,
      16, 0, 0);
}

// ---------------- front end ----------------

// x (B,T,65) -> hpbf (B,T,128) = silu(pointconv), bf16
__global__ void front_pointconv(const float* __restrict__ x, const float* __restrict__ pw,
                                const float* __restrict__ pb, __hip_bfloat16* __restrict__ hpbf) {
  int t = blockIdx.x, b = blockIdx.y, c = threadIdx.x;  // 128 threads
  __shared__ float xs[64];
  if (c < 64) xs[c] = x[((size_t)b * T + t) * 65 + c];
  __syncthreads();
  float acc = pb[c];
  const float4* pwr = (const float4*)(pw + c * 64);
#pragma unroll
  for (int i = 0; i < 16; ++i) {
    float4 w4 = pwr[i];
    acc = fmaf(w4.x, xs[4 * i + 0], acc);
    acc = fmaf(w4.y, xs[4 * i + 1], acc);
    acc = fmaf(w4.z, xs[4 * i + 2], acc);
    acc = fmaf(w4.w, xs[4 * i + 3], acc);
  }
  hpbf[((size_t)b * T + t) * 128 + c] = __float2bfloat16(siluf(acc));
}

// hpbf (B,T,128) -> Xim (BT, 3456) bf16, col j*128+ci = hpbf[b, t-13+j, ci]
__global__ void im2col_front(const __hip_bfloat16* __restrict__ hpbf,
                             __hip_bfloat16* __restrict__ Xim) {
  int idx = blockIdx.x * 256 + threadIdx.x;  // BT*432 threads, 16B each
  if (idx >= BT * 432) return;
  int row = idx / 432, r = idx - row * 432;
  int j = r >> 4, seg = r & 15;
  int b = row >> 9, t = row & 511;
  int ts = t - 13 + j;
  uint4 v = {0u, 0u, 0u, 0u};
  if (ts >= 0 && ts < T) v = *(const uint4*)(hpbf + ((size_t)(b * T + ts)) * 128 + seg * 8);
  *(uint4*)(Xim + (size_t)row * KCONV + j * 128 + seg * 8) = v;
}

// c1w(256,128,3), c2w(256,128,9), c3w(256,128,27) -> Wfr(768, 3456) bf16
__global__ void build_conv_w(const float* __restrict__ c1w, const float* __restrict__ c2w,
                             const float* __restrict__ c3w, __hip_bfloat16* __restrict__ Wfr) {
  int total = NCONV * KCONV;
  for (int idx = blockIdx.x * 256 + threadIdx.x; idx < total; idx += gridDim.x * 256) {
    int co = idx / KCONV, r = idx - co * KCONV;
    int j = r >> 7, ci = r & 127;
    float v = 0.f;
    if (co < 256) {
      int k = j - 12;
      if (k >= 0 && k < 3) v = c1w[((size_t)co * 128 + ci) * 3 + k];
    } else if (co < 512) {
      int k = j - 9;
      if (k >= 0 && k < 9) v = c2w[((size_t)(co - 256) * 128 + ci) * 9 + k];
    } else {
      v = c3w[((size_t)(co - 512) * 128 + ci) * 27 + j];
    }
    Wfr[idx] = __float2bfloat16(v);
  }
}

__global__ void build_conv_b(const float* __restrict__ b1, const float* __restrict__ b2,
                             const float* __restrict__ b3, float* __restrict__ cb) {
  int i = blockIdx.x * 256 + threadIdx.x;
  if (i >= NCONV) return;
  cb[i] = (i < 256) ? b1[i] : (i < 512) ? b2[i - 256] : b3[i - 512];
}

__global__ void fill_pe(const float* __restrict__ x, float* __restrict__ h) {
  int i = blockIdx.x * 256 + threadIdx.x;
  if (i < BT) h[(size_t)i * D_MODEL + 768] = x[(size_t)i * 65 + 64];
}

// ---------------- helpers ----------------

// f32 (N,K) -> bf16 (Npad,Kpad) zero-padded
__global__ void cvt_pad(const float* __restrict__ src, __hip_bfloat16* __restrict__ dst,
                        int N, int K, int Npad, int Kpad) {
  int total = Npad * Kpad;
  for (int idx = blockIdx.x * 256 + threadIdx.x; idx < total; idx += gridDim.x * 256) {
    int n = idx / Kpad, k = idx - n * Kpad;
    float v = (n < N && k < K) ? src[(size_t)n * K + k] : 0.f;
    dst[idx] = __float2bfloat16(v);
  }
}

__global__ void zero_pad_cols(__hip_bfloat16* __restrict__ buf, int rows, int ld, int c0) {
  int w = ld - c0;
  int total = rows * w;
  int idx = blockIdx.x * 256 + threadIdx.x;
  if (idx < total) buf[(size_t)(idx / w) * ld + c0 + (idx % w)] = __float2bfloat16(0.f);
}

// rmsnorm row (769) -> bf16 padded row (832)
__global__ __launch_bounds__(256) void rmsnorm_bf(const float* __restrict__ h,
                                                  const float* __restrict__ w,
                                                  __hip_bfloat16* __restrict__ ubf) {
  int row = blockIdx.x;
  const float* hr = h + (size_t)row * D_MODEL;
  __shared__ float red[4];
  int wid = threadIdx.x >> 6, lane = threadIdx.x & 63;
  float ss = 0.f;
  for (int i = threadIdx.x; i < D_MODEL; i += 256) { float v = hr[i]; ss = fmaf(v, v, ss); }
  ss = wredx(ss);
  if (lane == 0) red[wid] = ss;
  __syncthreads();
  float tot = red[0] + red[1] + red[2] + red[3];
  float sc = rsqrtf(tot * (1.f / D_MODEL) + 1e-6f);
  for (int i = threadIdx.x; i < KP_MODEL; i += 256) {
    float v = (i < D_MODEL) ? hr[i] * sc * w[i] : 0.f;
    ubf[(size_t)row * KP_MODEL + i] = __float2bfloat16(v);
  }
}

// ---------------- bf16 MFMA GEMM:  C[m][n] = sum_k A[m][k] * W[n][k] (+ epilogue) ----------------
// EPI 0: plain f32; 1: softplus(acc+bias[n]) -> dtdu float2 {dt, dt*du} in (b,t,d);
// 6: split-K raw partial store; 7: bf16 store to auxb[m*ldc+n]
template <int EPI>
__global__ __launch_bounds__(256) void gemm_bf16(const __hip_bfloat16* __restrict__ A,
                                                 const __hip_bfloat16* __restrict__ W,
                                                 float* __restrict__ C, int M, int Nreal, int Kp,
                                                 const float* extra, int ldadd, int ldc,
                                                 float2* auxv, __hip_bfloat16* auxb,
                                                 const __hip_bfloat16* auxr) {
  __shared__ __align__(16) __hip_bfloat16 As[128 * 64];
  __shared__ __align__(16) __hip_bfloat16 Bs[128 * 64];
  const int tid = threadIdx.x;
  const int wid = tid >> 6, lane = tid & 63;
  const int wr = wid >> 1, wc = wid & 1;
  const int m0 = blockIdx.y * 128, n0 = blockIdx.x * 128;
  f32x4 acc[4][4] = {};
  const int lrow = lane >> 3;                                 // row within 8-row segment
  const int cbyte = ((lane & 7) << 4) ^ (lrow << 4);          // inverse-swizzled source col byte
  const char* Ab = (const char*)A;
  const char* Wb = (const char*)W;
  const size_t strideAB = (size_t)Kp * 2;
  const int swz = (lane & 7) << 4;

  int kbeg = 0, kend = Kp;
  if constexpr (EPI == 6) {
    int khalf = (((Kp >> 1) + 63) >> 6) << 6;
    if (blockIdx.z == 0) kend = khalf; else kbeg = khalf;
  }

  for (int k0 = kbeg; k0 < kend; k0 += 64) {
#pragma unroll
    for (int i = 0; i < 4; ++i) {
      int seg = i * 4 + wid;                                  // wave-uniform
      int row = seg * 8 + lrow;
      gload_lds16(Ab + (size_t)(m0 + row) * strideAB + k0 * 2 + cbyte, (char*)As + seg * 1024);
      gload_lds16(Wb + (size_t)(n0 + row) * strideAB + k0 * 2 + cbyte, (char*)Bs + seg * 1024);
    }
    __syncthreads();
#pragma unroll
    for (int kk = 0; kk < 2; ++kk) {
      int kb = kk * 64 + ((lane >> 4) << 4);                  // byte offset of this lane's 8 bf16
      bf16x8v af[4], bfr[4];
#pragma unroll
      for (int mi = 0; mi < 4; ++mi) {
        int row = wr * 64 + mi * 16 + (lane & 15);
        af[mi] = *(const bf16x8v*)((const char*)As + row * 128 + (kb ^ swz));
      }
#pragma unroll
      for (int ni = 0; ni < 4; ++ni) {
        int row = wc * 64 + ni * 16 + (lane & 15);
        bfr[ni] = *(const bf16x8v*)((const char*)Bs + row * 128 + (kb ^ swz));
      }
#pragma unroll
      for (int mi = 0; mi < 4; ++mi)
#pragma unroll
        for (int ni = 0; ni < 4; ++ni)
          acc[mi][ni] = __builtin_amdgcn_mfma_f32_16x16x32_bf16(af[mi], bfr[ni], acc[mi][ni], 0, 0, 0);
    }
    __syncthreads();
  }

#pragma unroll
  for (int mi = 0; mi < 4; ++mi) {
#pragma unroll
    for (int ni = 0; ni < 4; ++ni) {
      int n = n0 + wc * 64 + ni * 16 + (lane & 15);
      if (n < Nreal) {
        int mb = m0 + wr * 64 + mi * 16 + ((lane >> 4) << 2);
#pragma unroll
        for (int v = 0; v < 4; ++v) {
          float val = acc[mi][ni][v];
          int m = mb + v;
          if constexpr (EPI == 1) {
            val += extra[n];
            val = fmaxf(val, 0.f) + log1pf(__expf(-fabsf(val)));   // stable softplus
            float du = __bfloat162float(auxr[(size_t)m * KP_INNER + n]);
            auxv[(size_t)m * D_INNER + n] = make_float2(val, val * du);   // (b,t,d) coalesced
          } else if constexpr (EPI == 6) {
            C[((size_t)blockIdx.z * M + m) * ldc + n] = val;
          } else if constexpr (EPI == 7) {
            auxb[(size_t)m * ldc + n] = __float2bfloat16(val);
          } else {
            C[(size_t)m * ldc + n] = val;
          }
        }
      }
    }
  }
}

// ---------------- split-K combine kernels ----------------
__global__ void combine_conv(const float* __restrict__ p, const float* __restrict__ cb,
                             float* __restrict__ h) {
  int i = blockIdx.x * 256 + threadIdx.x;
  if (i >= BT * NCONV) return;
  int m = i / NCONV, n = i - m * NCONV;
  float v = p[i] + p[(size_t)BT * NCONV + i] + cb[n];
  h[(size_t)m * D_MODEL + n] = siluf(v);
}

// x_proj combine: parts (2, BT, 256) -> dtbf (BT,64) bf16 + bcbf (BT,64) packed {B,C} bf16x2
__global__ void combine_xproj(const float* __restrict__ p, __hip_bfloat16* __restrict__ dtbf,
                              __hip_bfloat16* __restrict__ bcb) {
  int i = blockIdx.x * 256 + threadIdx.x;
  if (i >= BT * 192) return;
  int m = i / 192, n = i - m * 192;
  if (n >= DT_RANK + 2 * D_STATE) return;
  float v = p[(size_t)m * 256 + n] + p[(size_t)(BT + m) * 256 + n];
  if (n < 64) dtbf[(size_t)m * 64 + n] = __float2bfloat16(n < DT_RANK ? v : 0.f);
  if (n >= DT_RANK && n < DT_RANK + D_STATE)
    bcb[((size_t)m * 64 + (n - DT_RANK)) * 2] = __float2bfloat16(v);          // B -> lo
  else if (n >= DT_RANK + D_STATE)
    bcb[((size_t)m * 64 + (n - DT_RANK - D_STATE)) * 2 + 1] = __float2bfloat16(v);  // C -> hi
}

__global__ void combine_out(const float* __restrict__ p, float* __restrict__ h) {
  int i = blockIdx.x * 256 + threadIdx.x;
  if (i >= BT * D_MODEL) return;
  h[i] += p[i] + p[(size_t)BT * D_MODEL + i];
}

// ---------------- depthwise causal conv (k=4) + silu -> bf16 only ----------------
__global__ void dwconv_silu(const __hip_bfloat16* __restrict__ xz, const float* __restrict__ cw,
                            const float* __restrict__ cb, __hip_bfloat16* __restrict__ xinbf) {
  int idx = blockIdx.x * 256 + threadIdx.x;
  if (idx >= BT * D_INNER) return;
  int bt = idx / D_INNER;
  int d = idx - bt * D_INNER;
  int t = bt & (T - 1);
  float acc = cb[d];
  const __hip_bfloat16* col = xz + (size_t)bt * D2 + d;
#pragma unroll
  for (int k = 0; k < 4; ++k) {
    int tt = t + k - 3;
    float v = (tt >= 0) ? __bfloat162float(col[(ptrdiff_t)(k - 3) * D2]) : 0.f;
    acc = fmaf(cw[d * 4 + k], v, acc);
  }
  acc = siluf(acc);
  xinbf[(size_t)bt * KP_INNER + d] = __float2bfloat16(acc);
}

// ---------------- fused single-pass selective scan ----------------
// block = 512 threads = 8 waves = 8 consecutive d, one b; wave walks full T=512.
// bc: coalesced global register double-buffer; dt/dtu: block-exclusive 128B lines
// (8 consecutive d x float2), uniform loads, L1-shared across the 8 waves.
// Reduce: DPP folds (xor1/2 via quad_perm, xor8 via row_ror) + 3 DS swizzle/shfl.
// fold order (xor1, xor2, xor4) -> output slot = bit-reverse(lane&7) = brl.

#define FLD(BC, DQ, DU, ZV, T0)                                              \
  {                                                                          \
    _Pragma("unroll") for (int k = 0; k < 8; ++k) {                          \
      BC[k] = bgp[(size_t)((T0) + k) * 64];                                  \
      DQ[k] = dqp[(size_t)((T0) + k) * D_INNER];                             \
    }                                                                        \
    size_t ts = (size_t)((T0) + brl);                                        \
    DU = __bfloat162float(xp[ts * KP_INNER]);                                \
    ZV = __bfloat162float(zp[ts * D2]);                                      \
  }

#define FCOMP(BC, DQ, DU, ZV, T0)                                            \
  {                                                                          \
    float vv[8];                                                             \
    _Pragma("unroll") for (int k = 0; k < 8; ++k) {                          \
      float Bv = __uint_as_float(BC[k] << 16);                               \
      float Cv = __uint_as_float(BC[k] & 0xffff0000u);                       \
      h = fmaf(fexp2(DQ[k].x * a2), h, DQ[k].y * Bv);                        \
      vv[k] = h * Cv;                                                        \
    }                                                                        \
    _Pragma("unroll") for (int k = 0; k < 4; ++k) {                          \
      float snd = bb0 ? vv[k] : vv[k + 4];                                   \
      float kp = bb0 ? vv[k + 4] : vv[k];                                    \
      vv[k] = kp + DPPF(snd, 0xB1);                                          \
    }                                                                        \
    _Pragma("unroll") for (int k = 0; k < 2; ++k) {                          \
      float snd = bb1 ? vv[k] : vv[k + 2];                                   \
      float kp = bb1 ? vv[k + 2] : vv[k];                                    \
      vv[k] = kp + DPPF(snd, 0x4E);                                          \
    }                                                                        \
    {                                                                        \
      float snd = bb2 ? vv[0] : vv[1];                                       \
      float kp = bb2 ? vv[1] : vv[0];                                        \
      vv[0] = kp + SWZF(snd, 0x101F);                                        \
    }                                                                        \
    float y = vv[0];                                                         \
    y += DPPF(y, 0x128);                                                     \
    y += SWZF(y, 0x401F);                                                    \
    y += __shfl_xor(y, 32);                                                  \
    if (lane < 8 && valid) {                                                 \
      float yo = (y + DU * dsk) * siluf(ZV);                                 \
      ybf[(rb + (T0) + brl) * KP_INNER + d] = __float2bfloat16(yo);          \
    }                                                                        \
  }

__global__ __launch_bounds__(512) void scan_fused(const uint* __restrict__ bcp16,
                                                  const float2* __restrict__ dtdu,
                                                  const __hip_bfloat16* __restrict__ xinbf,
                                                  const __hip_bfloat16* __restrict__ xzbf,
                                                  const float* __restrict__ A_log,
                                                  const float* __restrict__ Dskip,
                                                  __hip_bfloat16* __restrict__ ybf) {
  int tid = threadIdx.x, wid = tid >> 6, lane = tid & 63;
  int dg = blockIdx.x % DG8, b = blockIdx.x / DG8;
  int d = dg * 8 + wid;
  bool valid = (d < D_INNER);
  int dc = valid ? d : (D_INNER - 1);
  const bool bb2 = lane & 4, bb1 = lane & 2, bb0 = lane & 1;
  const int brl = ((lane & 1) << 2) | (lane & 2) | ((lane & 4) >> 2);
  float a2 = -__expf(A_log[(size_t)dc * D_STATE + lane]) * 1.44269504f;
  float dsk = Dskip[dc];
  float h = 0.f;
  const size_t rb = (size_t)b * T;
  const uint* bgp = bcp16 + rb * 64 + lane;
  const float2* dqp = dtdu + rb * D_INNER + dc;
  const __hip_bfloat16* xp = xinbf + rb * KP_INNER + dc;
  const __hip_bfloat16* zp = xzbf + rb * D2 + D_INNER + dc;

  uint bA[8], bB[8];
  float2 dqA[8], dqB[8];
  float duA, zvA, duB, zvB;
  FLD(bA, dqA, duA, zvA, 0);
  for (int t0 = 0; t0 < T; t0 += 16) {
    FLD(bB, dqB, duB, zvB, t0 + 8);
    FCOMP(bA, dqA, duA, zvA, t0);
    if (t0 + 16 < T) FLD(bA, dqA, duA, zvA, t0 + 16);
    FCOMP(bB, dqB, duB, zvB, t0 + 8);
  }
}

// ---------------- final layernorm + classifier ----------------
__global__ __launch_bounds__(256) void ln_head(const float* __restrict__ h,
                                               const float* __restrict__ lnw,
                                               const float* __restrict__ lnb,
                                               const float* __restrict__ ow,
                                               const float* __restrict__ ob,
                                               float* __restrict__ out) {
  int row = blockIdx.x;
  const float* hr = h + (size_t)row * D_MODEL;
  __shared__ float sh[D_MODEL];
  __shared__ float red[4];
  int wid = threadIdx.x >> 6, lane = threadIdx.x & 63;
  float s = 0.f;
  for (int i = threadIdx.x; i < D_MODEL; i += 256) { float v = hr[i]; sh[i] = v; s += v; }
  s = wredx(s);
  if (lane == 0) red[wid] = s;
  __syncthreads();
  float mean = (red[0] + red[1] + red[2] + red[3]) * (1.f / D_MODEL);
  __syncthreads();
  float vs = 0.f;
  for (int i = threadIdx.x; i < D_MODEL; i += 256) { float dd = sh[i] - mean; vs = fmaf(dd, dd, vs); }
  vs = wredx(vs);
  if (lane == 0) red[wid] = vs;
  __syncthreads();
  float var = (red[0] + red[1] + red[2] + red[3]) * (1.f / D_MODEL);
  float inv = rsqrtf(var + 1e-5f);
  for (int i = threadIdx.x; i < D_MODEL; i += 256)
    sh[i] = (sh[i] - mean) * inv * lnw[i] + lnb[i];
  __syncthreads();
  for (int c = wid; c < 10; c += 4) {
    float acc = 0.f;
    for (int i = lane; i < D_MODEL; i += 64) acc = fmaf(sh[i], ow[(size_t)c * D_MODEL + i], acc);
    acc = wredx(acc);
    if (lane == 0) out[(size_t)row * 10 + c] = acc + ob[c];
  }
}

// ---------------- launcher ----------------
extern "C" void kernel_launch(void* const* d_in, const int* in_sizes, int n_in,
                              void* d_out, int out_size, void* d_ws, size_t ws_size,
                              hipStream_t stream) {
  const float* x    = (const float*)d_in[0];
  const float* pcw  = (const float*)d_in[1];
  const float* pcb  = (const float*)d_in[2];
  const float* c1w  = (const float*)d_in[3];
  const float* c1b  = (const float*)d_in[4];
  const float* c2w  = (const float*)d_in[5];
  const float* c2b  = (const float*)d_in[6];
  const float* c3w  = (const float*)d_in[7];
  const float* c3b  = (const float*)d_in[8];
  const float* lnw  = (const float*)d_in[9];
  const float* lnb  = (const float*)d_in[10];
  const float* ow   = (const float*)d_in[11];
  const float* ob   = (const float*)d_in[12];
  const float* rmsw = (const float*)d_in[13];
  const float* Wi   = (const float*)d_in[14];
  const float* dww  = (const float*)d_in[15];
  const float* dwb  = (const float*)d_in[16];
  const float* Wx   = (const float*)d_in[17];
  const float* Wdt  = (const float*)d_in[18];
  const float* dtbv = (const float*)d_in[19];
  const float* Alog = (const float*)d_in[20];
  const float* Dsk  = (const float*)d_in[21];
  const float* Wo   = (const float*)d_in[22];
  float* out = (float*)d_out;

  char* w = (char*)d_ws;
  auto alloc = [&](size_t n) { char* p = w; w += (n + 255) & ~(size_t)255; return p; };
  // shared region: front-end buffers (dead after front GEMM) aliased with scan temps
  constexpr size_t REGION = 26400000;
  char* region = alloc(REGION);
  __hip_bfloat16* hpbf = (__hip_bfloat16*)region;                    // 524,288 B
  __hip_bfloat16* Xim  = (__hip_bfloat16*)(region + 600064);         // 14,155,776 B
  __hip_bfloat16* Wfr  = (__hip_bfloat16*)(region + 14755840 + 256); // 5,308,416 B
  float* cb768         = (float*)(region + 20065024);                // 3,072 B
  float2* dtduT        = (float2*)region;                            // 25,198,592 B (layer phase)
  __hip_bfloat16* bcbf = (__hip_bfloat16*)(region + 25198592);       // 524,288 B packed {B,C}

  float* hbuf          = (float*)alloc((size_t)BT * D_MODEL * 4);
  __hip_bfloat16* ubf  = (__hip_bfloat16*)alloc((size_t)BT * KP_MODEL * 2);
  __hip_bfloat16* xzbf = (__hip_bfloat16*)alloc((size_t)BT * D2 * 2);
  __hip_bfloat16* xinbf= (__hip_bfloat16*)alloc((size_t)BT * KP_INNER * 2);
  __hip_bfloat16* dtbf = (__hip_bfloat16*)alloc((size_t)BT * KP_DT * 2);
  __hip_bfloat16* ybf  = (__hip_bfloat16*)alloc((size_t)BT * KP_INNER * 2);
  __hip_bfloat16* Wibf = (__hip_bfloat16*)alloc((size_t)NP_IN * KP_MODEL * 2);
  __hip_bfloat16* Wxbf = (__hip_bfloat16*)alloc((size_t)NP_X * KP_INNER * 2);
  __hip_bfloat16* Wdtbf= (__hip_bfloat16*)alloc((size_t)NP_DT * KP_DT * 2);
  __hip_bfloat16* Wobf = (__hip_bfloat16*)alloc((size_t)NP_OUT * KP_INNER * 2);
  float* parts         = (float*)alloc((size_t)2 * BT * D_MODEL * 4);          // 12.6 MB split-K partials

  front_pointconv<<<dim3(T, B), 128, 0, stream>>>(x, pcw, pcb, hpbf);
  im2col_front<<<(BT * 432) / 256, 256, 0, stream>>>(hpbf, Xim);
  build_conv_w<<<2048, 256, 0, stream>>>(c1w, c2w, c3w, Wfr);
  build_conv_b<<<3, 256, 0, stream>>>(c1b, c2b, c3b, cb768);
  gemm_bf16<6><<<dim3(NCONV / 128, BT / 128, 2), 256, 0, stream>>>(Xim, Wfr, parts, BT, NCONV, KCONV,
                                                                   nullptr, 0, NCONV,
                                                                   nullptr, nullptr, nullptr);
  combine_conv<<<(BT * NCONV + 255) / 256, 256, 0, stream>>>(parts, cb768, hbuf);
  fill_pe<<<(BT + 255) / 256, 256, 0, stream>>>(x, hbuf);
  // pad columns written once (scan/dwconv never touch cols >= D_INNER)
  zero_pad_cols<<<(BT * (KP_INNER - D_INNER) + 255) / 256, 256, 0, stream>>>(xinbf, BT, KP_INNER, D_INNER);
  zero_pad_cols<<<(BT * (KP_INNER - D_INNER) + 255) / 256, 256, 0, stream>>>(ybf, BT, KP_INNER, D_INNER);

  for (int l = 0; l < NLAYER; ++l) {
    const float* Al = Alog + (size_t)l * D_INNER * D_STATE;
    cvt_pad<<<2048, 256, 0, stream>>>(Wi + (size_t)l * D2 * D_MODEL, Wibf, D2, D_MODEL, NP_IN, KP_MODEL);
    cvt_pad<<<512, 256, 0, stream>>>(Wx + (size_t)l * (DT_RANK + 2 * D_STATE) * D_INNER, Wxbf,
                                     DT_RANK + 2 * D_STATE, D_INNER, NP_X, KP_INNER);
    cvt_pad<<<256, 256, 0, stream>>>(Wdt + (size_t)l * D_INNER * DT_RANK, Wdtbf, D_INNER, DT_RANK, NP_DT, KP_DT);
    cvt_pad<<<1024, 256, 0, stream>>>(Wo + (size_t)l * D_MODEL * D_INNER, Wobf, D_MODEL, D_INNER, NP_OUT, KP_INNER);

    rmsnorm_bf<<<BT, 256, 0, stream>>>(hbuf, rmsw + (size_t)l * D_MODEL, ubf);
    gemm_bf16<7><<<dim3(NP_IN / 128, BT / 128), 256, 0, stream>>>(ubf, Wibf, nullptr, BT, D2, KP_MODEL,
                                                                  nullptr, 0, D2,
                                                                  nullptr, xzbf, nullptr);
    dwconv_silu<<<(BT * D_INNER + 255) / 256, 256, 0, stream>>>(xzbf, dww + (size_t)l * D_INNER * 4,
                                                                dwb + (size_t)l * D_INNER, xinbf);
    gemm_bf16<6><<<dim3(NP_X / 128, BT / 128, 2), 256, 0, stream>>>(xinbf, Wxbf, parts, BT,
                                                                    DT_RANK + 2 * D_STATE, KP_INNER,
                                                                    nullptr, 0, 256,
                                                                    nullptr, nullptr, nullptr);
    combine_xproj<<<(BT * 192 + 255) / 256, 256, 0, stream>>>(parts, dtbf, bcbf);
    gemm_bf16<1><<<dim3(NP_DT / 128, BT / 128), 256, 0, stream>>>(dtbf, Wdtbf, nullptr, BT, D_INNER, KP_DT,
                                                                  dtbv + (size_t)l * D_INNER, 0, 0,
                                                                  dtduT, nullptr, xinbf);
    scan_fused<<<dim3(B * DG8), 512, 0, stream>>>((const uint*)bcbf, dtduT, xinbf, xzbf, Al,
                                                  Dsk + (size_t)l * D_INNER, ybf);
    gemm_bf16<6><<<dim3(NP_OUT / 128, BT / 128, 2), 256, 0, stream>>>(ybf, Wobf, parts, BT, D_MODEL, KP_INNER,
                                                                      nullptr, 0, D_MODEL,
                                                                      nullptr, nullptr, nullptr);
    combine_out<<<(BT * D_MODEL + 255) / 256, 256, 0, stream>>>(parts, hbuf);
  }
  ln_head<<<BT, 256, 0, stream>>>(hbuf, lnw, lnb, ow, ob, out);
}

// Round 12
// 595.938 us; speedup vs baseline: 1.2900x; 1.2900x over previous
//
#include <hip/hip_runtime.h>
#include <hip/hip_bf16.h>
#include <cstdint>
#include <math.h>

#define DEV static __device__ __forceinline__

typedef __attribute__((ext_vector_type(8))) __bf16 bf16x8v;
typedef __attribute__((ext_vector_type(4))) float f32x4;

constexpr int B = 4, T = 512, BT = B * T;
constexpr int D_MODEL = 769, D_INNER = 1538, D2 = 3076;
constexpr int DT_RANK = 49, D_STATE = 64;
constexpr int NLAYER = 2;
constexpr int NCH = 8, CHT = 64;           // fused scan: 8 chunks x 64 t
constexpr int DGRP = (D_INNER + 15) / 16;  // 97 d-groups of 16
// padded GEMM dims (K multiple of 64, N multiple of 128)
constexpr int KP_MODEL = 832;   // 769
constexpr int KP_INNER = 1600;  // 1538
constexpr int KP_DT    = 64;    // 49
constexpr int NP_IN  = 3200;    // 3076
constexpr int NP_X   = 256;     // 177
constexpr int NP_DT  = 1664;    // 1538
constexpr int NP_OUT = 896;     // 769
constexpr int KCONV  = 3456;    // 27*128 unified front-conv reduction
constexpr int NCONV  = 768;

DEV float siluf(float v) { return v / (1.f + __expf(-v)); }
DEV float fexp2(float x) { return __builtin_amdgcn_exp2f(x); }   // raw v_exp_f32

DEV float wredx(float v) {
#pragma unroll
  for (int o = 1; o < 64; o <<= 1) v += __shfl_xor(v, o);
  return v;
}

// DPP / swizzle cross-lane helpers (VALU-pipe DPP where possible)
#define DPPF(v, ctrl) __uint_as_float((uint)__builtin_amdgcn_mov_dpp((int)__float_as_uint(v), (ctrl), 0xf, 0xf, true))
#define SWZF(v, pat) __uint_as_float((uint)__builtin_amdgcn_ds_swizzle((int)__float_as_uint(v), (pat)))

DEV void gload_lds16(const void* g, void* l) {
  __builtin_amdgcn_global_load_lds(
      (const __attribute__((address_space(1))) uint32_t*)(uintptr_t)g,
      (__attribute__((address_space(3))) uint32_t*)(uint32_t)(uintptr_t)l,
      16, 0, 0);
}

// ---------------- front end ----------------

// x (B,T,65) -> hpbf (B,T,128) = silu(pointconv), bf16
__global__ void front_pointconv(const float* __restrict__ x, const float* __restrict__ pw,
                                const float* __restrict__ pb, __hip_bfloat16* __restrict__ hpbf) {
  int t = blockIdx.x, b = blockIdx.y, c = threadIdx.x;  // 128 threads
  __shared__ float xs[64];
  if (c < 64) xs[c] = x[((size_t)b * T + t) * 65 + c];
  __syncthreads();
  float acc = pb[c];
  const float4* pwr = (const float4*)(pw + c * 64);
#pragma unroll
  for (int i = 0; i < 16; ++i) {
    float4 w4 = pwr[i];
    acc = fmaf(w4.x, xs[4 * i + 0], acc);
    acc = fmaf(w4.y, xs[4 * i + 1], acc);
    acc = fmaf(w4.z, xs[4 * i + 2], acc);
    acc = fmaf(w4.w, xs[4 * i + 3], acc);
  }
  hpbf[((size_t)b * T + t) * 128 + c] = __float2bfloat16(siluf(acc));
}

// hpbf (B,T,128) -> Xim (BT, 3456) bf16, col j*128+ci = hpbf[b, t-13+j, ci]
__global__ void im2col_front(const __hip_bfloat16* __restrict__ hpbf,
                             __hip_bfloat16* __restrict__ Xim) {
  int idx = blockIdx.x * 256 + threadIdx.x;  // BT*432 threads, 16B each
  if (idx >= BT * 432) return;
  int row = idx / 432, r = idx - row * 432;
  int j = r >> 4, seg = r & 15;
  int b = row >> 9, t = row & 511;
  int ts = t - 13 + j;
  uint4 v = {0u, 0u, 0u, 0u};
  if (ts >= 0 && ts < T) v = *(const uint4*)(hpbf + ((size_t)(b * T + ts)) * 128 + seg * 8);
  *(uint4*)(Xim + (size_t)row * KCONV + j * 128 + seg * 8) = v;
}

// c1w(256,128,3), c2w(256,128,9), c3w(256,128,27) -> Wfr(768, 3456) bf16
__global__ void build_conv_w(const float* __restrict__ c1w, const float* __restrict__ c2w,
                             const float* __restrict__ c3w, __hip_bfloat16* __restrict__ Wfr) {
  int total = NCONV * KCONV;
  for (int idx = blockIdx.x * 256 + threadIdx.x; idx < total; idx += gridDim.x * 256) {
    int co = idx / KCONV, r = idx - co * KCONV;
    int j = r >> 7, ci = r & 127;
    float v = 0.f;
    if (co < 256) {
      int k = j - 12;
      if (k >= 0 && k < 3) v = c1w[((size_t)co * 128 + ci) * 3 + k];
    } else if (co < 512) {
      int k = j - 9;
      if (k >= 0 && k < 9) v = c2w[((size_t)(co - 256) * 128 + ci) * 9 + k];
    } else {
      v = c3w[((size_t)(co - 512) * 128 + ci) * 27 + j];
    }
    Wfr[idx] = __float2bfloat16(v);
  }
}

__global__ void build_conv_b(const float* __restrict__ b1, const float* __restrict__ b2,
                             const float* __restrict__ b3, float* __restrict__ cb) {
  int i = blockIdx.x * 256 + threadIdx.x;
  if (i >= NCONV) return;
  cb[i] = (i < 256) ? b1[i] : (i < 512) ? b2[i - 256] : b3[i - 512];
}

__global__ void fill_pe(const float* __restrict__ x, float* __restrict__ h) {
  int i = blockIdx.x * 256 + threadIdx.x;
  if (i < BT) h[(size_t)i * D_MODEL + 768] = x[(size_t)i * 65 + 64];
}

// ---------------- helpers ----------------

// f32 (N,K) -> bf16 (Npad,Kpad) zero-padded
__global__ void cvt_pad(const float* __restrict__ src, __hip_bfloat16* __restrict__ dst,
                        int N, int K, int Npad, int Kpad) {
  int total = Npad * Kpad;
  for (int idx = blockIdx.x * 256 + threadIdx.x; idx < total; idx += gridDim.x * 256) {
    int n = idx / Kpad, k = idx - n * Kpad;
    float v = (n < N && k < K) ? src[(size_t)n * K + k] : 0.f;
    dst[idx] = __float2bfloat16(v);
  }
}

__global__ void zero_pad_cols(__hip_bfloat16* __restrict__ buf, int rows, int ld, int c0) {
  int w = ld - c0;
  int total = rows * w;
  int idx = blockIdx.x * 256 + threadIdx.x;
  if (idx < total) buf[(size_t)(idx / w) * ld + c0 + (idx % w)] = __float2bfloat16(0.f);
}

// rmsnorm row (769) -> bf16 padded row (832)
__global__ __launch_bounds__(256) void rmsnorm_bf(const float* __restrict__ h,
                                                  const float* __restrict__ w,
                                                  __hip_bfloat16* __restrict__ ubf) {
  int row = blockIdx.x;
  const float* hr = h + (size_t)row * D_MODEL;
  __shared__ float red[4];
  int wid = threadIdx.x >> 6, lane = threadIdx.x & 63;
  float ss = 0.f;
  for (int i = threadIdx.x; i < D_MODEL; i += 256) { float v = hr[i]; ss = fmaf(v, v, ss); }
  ss = wredx(ss);
  if (lane == 0) red[wid] = ss;
  __syncthreads();
  float tot = red[0] + red[1] + red[2] + red[3];
  float sc = rsqrtf(tot * (1.f / D_MODEL) + 1e-6f);
  for (int i = threadIdx.x; i < KP_MODEL; i += 256) {
    float v = (i < D_MODEL) ? hr[i] * sc * w[i] : 0.f;
    ubf[(size_t)row * KP_MODEL + i] = __float2bfloat16(v);
  }
}

// ---------------- bf16 MFMA GEMM:  C[m][n] = sum_k A[m][k] * W[n][k] (+ epilogue) ----------------
// EPI 0: plain f32; 1: softplus(acc+bias[n]) -> dtdu float2 {dt, dt*du} in (b,t,d);
// 6: split-K raw partial store; 7: bf16 store to auxb[m*ldc+n]
template <int EPI>
__global__ __launch_bounds__(256) void gemm_bf16(const __hip_bfloat16* __restrict__ A,
                                                 const __hip_bfloat16* __restrict__ W,
                                                 float* __restrict__ C, int M, int Nreal, int Kp,
                                                 const float* extra, int ldadd, int ldc,
                                                 float2* auxv, __hip_bfloat16* auxb,
                                                 const __hip_bfloat16* auxr) {
  __shared__ __align__(16) __hip_bfloat16 As[128 * 64];
  __shared__ __align__(16) __hip_bfloat16 Bs[128 * 64];
  const int tid = threadIdx.x;
  const int wid = tid >> 6, lane = tid & 63;
  const int wr = wid >> 1, wc = wid & 1;
  const int m0 = blockIdx.y * 128, n0 = blockIdx.x * 128;
  f32x4 acc[4][4] = {};
  const int lrow = lane >> 3;                                 // row within 8-row segment
  const int cbyte = ((lane & 7) << 4) ^ (lrow << 4);          // inverse-swizzled source col byte
  const char* Ab = (const char*)A;
  const char* Wb = (const char*)W;
  const size_t strideAB = (size_t)Kp * 2;
  const int swz = (lane & 7) << 4;

  int kbeg = 0, kend = Kp;
  if constexpr (EPI == 6) {
    int khalf = (((Kp >> 1) + 63) >> 6) << 6;
    if (blockIdx.z == 0) kend = khalf; else kbeg = khalf;
  }

  for (int k0 = kbeg; k0 < kend; k0 += 64) {
#pragma unroll
    for (int i = 0; i < 4; ++i) {
      int seg = i * 4 + wid;                                  // wave-uniform
      int row = seg * 8 + lrow;
      gload_lds16(Ab + (size_t)(m0 + row) * strideAB + k0 * 2 + cbyte, (char*)As + seg * 1024);
      gload_lds16(Wb + (size_t)(n0 + row) * strideAB + k0 * 2 + cbyte, (char*)Bs + seg * 1024);
    }
    __syncthreads();
#pragma unroll
    for (int kk = 0; kk < 2; ++kk) {
      int kb = kk * 64 + ((lane >> 4) << 4);                  // byte offset of this lane's 8 bf16
      bf16x8v af[4], bfr[4];
#pragma unroll
      for (int mi = 0; mi < 4; ++mi) {
        int row = wr * 64 + mi * 16 + (lane & 15);
        af[mi] = *(const bf16x8v*)((const char*)As + row * 128 + (kb ^ swz));
      }
#pragma unroll
      for (int ni = 0; ni < 4; ++ni) {
        int row = wc * 64 + ni * 16 + (lane & 15);
        bfr[ni] = *(const bf16x8v*)((const char*)Bs + row * 128 + (kb ^ swz));
      }
#pragma unroll
      for (int mi = 0; mi < 4; ++mi)
#pragma unroll
        for (int ni = 0; ni < 4; ++ni)
          acc[mi][ni] = __builtin_amdgcn_mfma_f32_16x16x32_bf16(af[mi], bfr[ni], acc[mi][ni], 0, 0, 0);
    }
    __syncthreads();
  }

#pragma unroll
  for (int mi = 0; mi < 4; ++mi) {
#pragma unroll
    for (int ni = 0; ni < 4; ++ni) {
      int n = n0 + wc * 64 + ni * 16 + (lane & 15);
      if (n < Nreal) {
        int mb = m0 + wr * 64 + mi * 16 + ((lane >> 4) << 2);
#pragma unroll
        for (int v = 0; v < 4; ++v) {
          float val = acc[mi][ni][v];
          int m = mb + v;
          if constexpr (EPI == 1) {
            val += extra[n];
            val = fmaxf(val, 0.f) + log1pf(__expf(-fabsf(val)));   // stable softplus
            float du = __bfloat162float(auxr[(size_t)m * KP_INNER + n]);
            auxv[(size_t)m * D_INNER + n] = make_float2(val, val * du);   // (b,t,d) coalesced
          } else if constexpr (EPI == 6) {
            C[((size_t)blockIdx.z * M + m) * ldc + n] = val;
          } else if constexpr (EPI == 7) {
            auxb[(size_t)m * ldc + n] = __float2bfloat16(val);
          } else {
            C[(size_t)m * ldc + n] = val;
          }
        }
      }
    }
  }
}

// ---------------- split-K combine kernels ----------------
__global__ void combine_conv(const float* __restrict__ p, const float* __restrict__ cb,
                             float* __restrict__ h) {
  int i = blockIdx.x * 256 + threadIdx.x;
  if (i >= BT * NCONV) return;
  int m = i / NCONV, n = i - m * NCONV;
  float v = p[i] + p[(size_t)BT * NCONV + i] + cb[n];
  h[(size_t)m * D_MODEL + n] = siluf(v);
}

// x_proj combine: parts (2, BT, 256) -> dtbf (BT,64) bf16 + bcbf (BT,64) packed {B,C} bf16x2
__global__ void combine_xproj(const float* __restrict__ p, __hip_bfloat16* __restrict__ dtbf,
                              __hip_bfloat16* __restrict__ bcb) {
  int i = blockIdx.x * 256 + threadIdx.x;
  if (i >= BT * 192) return;
  int m = i / 192, n = i - m * 192;
  if (n >= DT_RANK + 2 * D_STATE) return;
  float v = p[(size_t)m * 256 + n] + p[(size_t)(BT + m) * 256 + n];
  if (n < 64) dtbf[(size_t)m * 64 + n] = __float2bfloat16(n < DT_RANK ? v : 0.f);
  if (n >= DT_RANK && n < DT_RANK + D_STATE)
    bcb[((size_t)m * 64 + (n - DT_RANK)) * 2] = __float2bfloat16(v);          // B -> lo
  else if (n >= DT_RANK + D_STATE)
    bcb[((size_t)m * 64 + (n - DT_RANK - D_STATE)) * 2 + 1] = __float2bfloat16(v);  // C -> hi
}

__global__ void combine_out(const float* __restrict__ p, float* __restrict__ h) {
  int i = blockIdx.x * 256 + threadIdx.x;
  if (i >= BT * D_MODEL) return;
  h[i] += p[i] + p[(size_t)BT * D_MODEL + i];
}

// ---------------- depthwise causal conv (k=4) + silu -> bf16 only ----------------
__global__ void dwconv_silu(const __hip_bfloat16* __restrict__ xz, const float* __restrict__ cw,
                            const float* __restrict__ cb, __hip_bfloat16* __restrict__ xinbf) {
  int idx = blockIdx.x * 256 + threadIdx.x;
  if (idx >= BT * D_INNER) return;
  int bt = idx / D_INNER;
  int d = idx - bt * D_INNER;
  int t = bt & (T - 1);
  float acc = cb[d];
  const __hip_bfloat16* col = xz + (size_t)bt * D2 + d;
#pragma unroll
  for (int k = 0; k < 4; ++k) {
    int tt = t + k - 3;
    float v = (tt >= 0) ? __bfloat162float(col[(ptrdiff_t)(k - 3) * D2]) : 0.f;
    acc = fmaf(cw[d * 4 + k], v, acc);
  }
  acc = siluf(acc);
  xinbf[(size_t)bt * KP_INNER + d] = __float2bfloat16(acc);
}

// ---------------- fused single-pass scan, LDS-staged, double-buffered ----------------
// block = 1024 threads = 16 waves = 16 consecutive d, one b; wave walks full T=512 in
// 8 chunks of 64 t. Chunk c+1 staged into LDS buffer s^1 while computing chunk c from s;
// one __syncthreads per chunk. bc: global per-lane coalesced register double-buffer.
// Reduce: DPP folds + 3 DS ops; fold order (xor1,xor2,xor4) -> slot = brl (bit-reverse).

__global__ __launch_bounds__(1024) void scan_fused(const uint* __restrict__ bcp16,
                                                   const float2* __restrict__ dtdu,
                                                   const __hip_bfloat16* __restrict__ xinbf,
                                                   const __hip_bfloat16* __restrict__ xzbf,
                                                   const float* __restrict__ A_log,
                                                   const float* __restrict__ Dskip,
                                                   __hip_bfloat16* __restrict__ ybf) {
  __shared__ __align__(16) float dts[2][16 * 68];
  __shared__ __align__(16) float dtus[2][16 * 68];
  __shared__ float xins[2][CHT * 17];
  __shared__ float xzs[2][CHT * 17];
  int tid = threadIdx.x, wid = tid >> 6, lane = tid & 63;
  int dg = blockIdx.x % DGRP, b = blockIdx.x / DGRP;
  int d0 = dg * 16, d = d0 + wid;
  bool valid = (d < D_INNER);
  int dc = valid ? d : (D_INNER - 1);
  const size_t rb = (size_t)b * T;

  auto stage = [&](int c, int s) {
    // 1024 elements = exactly one per thread; fully coalesced, block-exclusive lines
    int tt = tid >> 4, dd = tid & 15;
    float2 dq = dtdu[(rb + c * CHT + tt) * D_INNER + d0 + dd];
    dts[s][dd * 68 + tt] = dq.x;
    dtus[s][dd * 68 + tt] = dq.y;
    xins[s][tt * 17 + dd] = __bfloat162float(xinbf[(rb + c * CHT + tt) * KP_INNER + d0 + dd]);
    xzs[s][tt * 17 + dd] = __bfloat162float(xzbf[(rb + c * CHT + tt) * D2 + D_INNER + d0 + dd]);
  };

  stage(0, 0);
  __syncthreads();

  const bool bb2 = lane & 4, bb1 = lane & 2, bb0 = lane & 1;
  const int brl = ((lane & 1) << 2) | (lane & 2) | ((lane & 4) >> 2);
  float a2 = -__expf(A_log[(size_t)dc * D_STATE + lane]) * 1.44269504f;
  float dsk = Dskip[dc];
  float h = 0.f;
  const uint* bgp = bcp16 + rb * 64 + lane;

  uint bA[8], bB[8];
#pragma unroll
  for (int k = 0; k < 8; ++k) bA[k] = bgp[k * 64];

  for (int g = 0; g < 64; ++g) {
    int ch = g >> 3, s = ch & 1, t0l = (g & 7) * 8, t0g = ch * CHT + t0l;
    if (t0l == 0 && ch + 1 < NCH) stage(ch + 1, s ^ 1);
    if (g + 1 < 64) {
#pragma unroll
      for (int k = 0; k < 8; ++k) bB[k] = bgp[(size_t)(t0g + 8 + k) * 64];
    }
    {
      float4 q0 = *(const float4*)&dts[s][wid * 68 + t0l];
      float4 q1 = *(const float4*)&dts[s][wid * 68 + t0l + 4];
      float4 u0 = *(const float4*)&dtus[s][wid * 68 + t0l];
      float4 u1 = *(const float4*)&dtus[s][wid * 68 + t0l + 4];
      float dtv[8] = {q0.x, q0.y, q0.z, q0.w, q1.x, q1.y, q1.z, q1.w};
      float duv[8] = {u0.x, u0.y, u0.z, u0.w, u1.x, u1.y, u1.z, u1.w};
      float vv[8];
#pragma unroll
      for (int k = 0; k < 8; ++k) {
        float Bv = __uint_as_float(bA[k] << 16);
        float Cv = __uint_as_float(bA[k] & 0xffff0000u);
        h = fmaf(fexp2(dtv[k] * a2), h, duv[k] * Bv);
        vv[k] = h * Cv;
      }
#pragma unroll
      for (int k = 0; k < 4; ++k) {
        float snd = bb0 ? vv[k] : vv[k + 4];
        float kp = bb0 ? vv[k + 4] : vv[k];
        vv[k] = kp + DPPF(snd, 0xB1);
      }
#pragma unroll
      for (int k = 0; k < 2; ++k) {
        float snd = bb1 ? vv[k] : vv[k + 2];
        float kp = bb1 ? vv[k + 2] : vv[k];
        vv[k] = kp + DPPF(snd, 0x4E);
      }
      {
        float snd = bb2 ? vv[0] : vv[1];
        float kp = bb2 ? vv[1] : vv[0];
        vv[0] = kp + SWZF(snd, 0x101F);
      }
      float y = vv[0];
      y += DPPF(y, 0x128);
      y += SWZF(y, 0x401F);
      y += __shfl_xor(y, 32);
      if (lane < 8 && valid) {
        float du_ = xins[s][(t0l + brl) * 17 + wid];
        float zv = xzs[s][(t0l + brl) * 17 + wid];
        float yo = (y + du_ * dsk) * siluf(zv);
        ybf[(rb + t0g + brl) * KP_INNER + d] = __float2bfloat16(yo);
      }
    }
#pragma unroll
    for (int k = 0; k < 8; ++k) bA[k] = bB[k];
    if (t0l == 56) __syncthreads();
  }
}

// ---------------- final layernorm + classifier ----------------
__global__ __launch_bounds__(256) void ln_head(const float* __restrict__ h,
                                               const float* __restrict__ lnw,
                                               const float* __restrict__ lnb,
                                               const float* __restrict__ ow,
                                               const float* __restrict__ ob,
                                               float* __restrict__ out) {
  int row = blockIdx.x;
  const float* hr = h + (size_t)row * D_MODEL;
  __shared__ float sh[D_MODEL];
  __shared__ float red[4];
  int wid = threadIdx.x >> 6, lane = threadIdx.x & 63;
  float s = 0.f;
  for (int i = threadIdx.x; i < D_MODEL; i += 256) { float v = hr[i]; sh[i] = v; s += v; }
  s = wredx(s);
  if (lane == 0) red[wid] = s;
  __syncthreads();
  float mean = (red[0] + red[1] + red[2] + red[3]) * (1.f / D_MODEL);
  __syncthreads();
  float vs = 0.f;
  for (int i = threadIdx.x; i < D_MODEL; i += 256) { float dd = sh[i] - mean; vs = fmaf(dd, dd, vs); }
  vs = wredx(vs);
  if (lane == 0) red[wid] = vs;
  __syncthreads();
  float var = (red[0] + red[1] + red[2] + red[3]) * (1.f / D_MODEL);
  float inv = rsqrtf(var + 1e-5f);
  for (int i = threadIdx.x; i < D_MODEL; i += 256)
    sh[i] = (sh[i] - mean) * inv * lnw[i] + lnb[i];
  __syncthreads();
  for (int c = wid; c < 10; c += 4) {
    float acc = 0.f;
    for (int i = lane; i < D_MODEL; i += 64) acc = fmaf(sh[i], ow[(size_t)c * D_MODEL + i], acc);
    acc = wredx(acc);
    if (lane == 0) out[(size_t)row * 10 + c] = acc + ob[c];
  }
}

// ---------------- launcher ----------------
extern "C" void kernel_launch(void* const* d_in, const int* in_sizes, int n_in,
                              void* d_out, int out_size, void* d_ws, size_t ws_size,
                              hipStream_t stream) {
  const float* x    = (const float*)d_in[0];
  const float* pcw  = (const float*)d_in[1];
  const float* pcb  = (const float*)d_in[2];
  const float* c1w  = (const float*)d_in[3];
  const float* c1b  = (const float*)d_in[4];
  const float* c2w  = (const float*)d_in[5];
  const float* c2b  = (const float*)d_in[6];
  const float* c3w  = (const float*)d_in[7];
  const float* c3b  = (const float*)d_in[8];
  const float* lnw  = (const float*)d_in[9];
  const float* lnb  = (const float*)d_in[10];
  const float* ow   = (const float*)d_in[11];
  const float* ob   = (const float*)d_in[12];
  const float* rmsw = (const float*)d_in[13];
  const float* Wi   = (const float*)d_in[14];
  const float* dww  = (const float*)d_in[15];
  const float* dwb  = (const float*)d_in[16];
  const float* Wx   = (const float*)d_in[17];
  const float* Wdt  = (const float*)d_in[18];
  const float* dtbv = (const float*)d_in[19];
  const float* Alog = (const float*)d_in[20];
  const float* Dsk  = (const float*)d_in[21];
  const float* Wo   = (const float*)d_in[22];
  float* out = (float*)d_out;

  char* w = (char*)d_ws;
  auto alloc = [&](size_t n) { char* p = w; w += (n + 255) & ~(size_t)255; return p; };
  // shared region: front-end buffers (dead after front GEMM) aliased with scan temps
  constexpr size_t REGION = 26400000;
  char* region = alloc(REGION);
  __hip_bfloat16* hpbf = (__hip_bfloat16*)region;                    // 524,288 B
  __hip_bfloat16* Xim  = (__hip_bfloat16*)(region + 600064);         // 14,155,776 B
  __hip_bfloat16* Wfr  = (__hip_bfloat16*)(region + 14755840 + 256); // 5,308,416 B
  float* cb768         = (float*)(region + 20065024);                // 3,072 B
  float2* dtduT        = (float2*)region;                            // 25,198,592 B (layer phase)
  __hip_bfloat16* bcbf = (__hip_bfloat16*)(region + 25198592);       // 524,288 B packed {B,C}

  float* hbuf          = (float*)alloc((size_t)BT * D_MODEL * 4);
  __hip_bfloat16* ubf  = (__hip_bfloat16*)alloc((size_t)BT * KP_MODEL * 2);
  __hip_bfloat16* xzbf = (__hip_bfloat16*)alloc((size_t)BT * D2 * 2);
  __hip_bfloat16* xinbf= (__hip_bfloat16*)alloc((size_t)BT * KP_INNER * 2);
  __hip_bfloat16* dtbf = (__hip_bfloat16*)alloc((size_t)BT * KP_DT * 2);
  __hip_bfloat16* ybf  = (__hip_bfloat16*)alloc((size_t)BT * KP_INNER * 2);
  __hip_bfloat16* Wibf = (__hip_bfloat16*)alloc((size_t)NP_IN * KP_MODEL * 2);
  __hip_bfloat16* Wxbf = (__hip_bfloat16*)alloc((size_t)NP_X * KP_INNER * 2);
  __hip_bfloat16* Wdtbf= (__hip_bfloat16*)alloc((size_t)NP_DT * KP_DT * 2);
  __hip_bfloat16* Wobf = (__hip_bfloat16*)alloc((size_t)NP_OUT * KP_INNER * 2);
  float* parts         = (float*)alloc((size_t)2 * BT * D_MODEL * 4);          // 12.6 MB split-K partials

  front_pointconv<<<dim3(T, B), 128, 0, stream>>>(x, pcw, pcb, hpbf);
  im2col_front<<<(BT * 432) / 256, 256, 0, stream>>>(hpbf, Xim);
  build_conv_w<<<2048, 256, 0, stream>>>(c1w, c2w, c3w, Wfr);
  build_conv_b<<<3, 256, 0, stream>>>(c1b, c2b, c3b, cb768);
  gemm_bf16<6><<<dim3(NCONV / 128, BT / 128, 2), 256, 0, stream>>>(Xim, Wfr, parts, BT, NCONV, KCONV,
                                                                   nullptr, 0, NCONV,
                                                                   nullptr, nullptr, nullptr);
  combine_conv<<<(BT * NCONV + 255) / 256, 256, 0, stream>>>(parts, cb768, hbuf);
  fill_pe<<<(BT + 255) / 256, 256, 0, stream>>>(x, hbuf);
  // pad columns written once (scan/dwconv never touch cols >= D_INNER)
  zero_pad_cols<<<(BT * (KP_INNER - D_INNER) + 255) / 256, 256, 0, stream>>>(xinbf, BT, KP_INNER, D_INNER);
  zero_pad_cols<<<(BT * (KP_INNER - D_INNER) + 255) / 256, 256, 0, stream>>>(ybf, BT, KP_INNER, D_INNER);

  for (int l = 0; l < NLAYER; ++l) {
    const float* Al = Alog + (size_t)l * D_INNER * D_STATE;
    cvt_pad<<<2048, 256, 0, stream>>>(Wi + (size_t)l * D2 * D_MODEL, Wibf, D2, D_MODEL, NP_IN, KP_MODEL);
    cvt_pad<<<512, 256, 0, stream>>>(Wx + (size_t)l * (DT_RANK + 2 * D_STATE) * D_INNER, Wxbf,
                                     DT_RANK + 2 * D_STATE, D_INNER, NP_X, KP_INNER);
    cvt_pad<<<256, 256, 0, stream>>>(Wdt + (size_t)l * D_INNER * DT_RANK, Wdtbf, D_INNER, DT_RANK, NP_DT, KP_DT);
    cvt_pad<<<1024, 256, 0, stream>>>(Wo + (size_t)l * D_MODEL * D_INNER, Wobf, D_MODEL, D_INNER, NP_OUT, KP_INNER);

    rmsnorm_bf<<<BT, 256, 0, stream>>>(hbuf, rmsw + (size_t)l * D_MODEL, ubf);
    gemm_bf16<7><<<dim3(NP_IN / 128, BT / 128), 256, 0, stream>>>(ubf, Wibf, nullptr, BT, D2, KP_MODEL,
                                                                  nullptr, 0, D2,
                                                                  nullptr, xzbf, nullptr);
    dwconv_silu<<<(BT * D_INNER + 255) / 256, 256, 0, stream>>>(xzbf, dww + (size_t)l * D_INNER * 4,
                                                                dwb + (size_t)l * D_INNER, xinbf);
    gemm_bf16<6><<<dim3(NP_X / 128, BT / 128, 2), 256, 0, stream>>>(xinbf, Wxbf, parts, BT,
                                                                    DT_RANK + 2 * D_STATE, KP_INNER,
                                                                    nullptr, 0, 256,
                                                                    nullptr, nullptr, nullptr);
    combine_xproj<<<(BT * 192 + 255) / 256, 256, 0, stream>>>(parts, dtbf, bcbf);
    gemm_bf16<1><<<dim3(NP_DT / 128, BT / 128), 256, 0, stream>>>(dtbf, Wdtbf, nullptr, BT, D_INNER, KP_DT,
                                                                  dtbv + (size_t)l * D_INNER, 0, 0,
                                                                  dtduT, nullptr, xinbf);
    scan_fused<<<dim3(B * DGRP), 1024, 0, stream>>>((const uint*)bcbf, dtduT, xinbf, xzbf, Al,
                                                    Dsk + (size_t)l * D_INNER, ybf);
    gemm_bf16<6><<<dim3(NP_OUT / 128, BT / 128, 2), 256, 0, stream>>>(ybf, Wobf, parts, BT, D_MODEL, KP_INNER,
                                                                      nullptr, 0, D_MODEL,
                                                                      nullptr, nullptr, nullptr);
    combine_out<<<(BT * D_MODEL + 255) / 256, 256, 0, stream>>>(parts, hbuf);
  }
  ln_head<<<BT, 256, 0, stream>>>(hbuf, lnw, lnb, ow, ob, out);
}

// Round 13
// 554.685 us; speedup vs baseline: 1.3859x; 1.0744x over previous
//
#include <hip/hip_runtime.h>
#include <hip/hip_bf16.h>
#include <cstdint>
#include <math.h>

#define DEV static __device__ __forceinline__

typedef __attribute__((ext_vector_type(8))) __bf16 bf16x8v;
typedef __attribute__((ext_vector_type(4))) float f32x4;

constexpr int B = 4, T = 512, BT = B * T;
constexpr int D_MODEL = 769, D_INNER = 1538, D2 = 3076;
constexpr int DT_RANK = 49, D_STATE = 64;
constexpr int NLAYER = 2;
constexpr int NCH = 8, CHT = 64;           // fused scan: 8 chunks x 64 t
constexpr int DGRP = (D_INNER + 15) / 16;  // 97 d-groups of 16
// padded GEMM dims (K multiple of 64, N multiple of 128)
constexpr int KP_MODEL = 832;   // 769
constexpr int KP_INNER = 1600;  // 1538
constexpr int KP_DT    = 64;    // 49
constexpr int NP_IN  = 3200;    // 3076
constexpr int NP_X   = 256;     // 177
constexpr int NP_DT  = 1664;    // 1538
constexpr int NP_OUT = 896;     // 769
constexpr int KCONV  = 3456;    // 27*128 unified front-conv reduction
constexpr int NCONV  = 768;

DEV float fexp2(float x) { return __builtin_amdgcn_exp2f(x); }   // raw v_exp_f32
DEV float flog2(float x) { return __builtin_amdgcn_logf(x); }    // raw v_log_f32
DEV float frcp(float x) { return __builtin_amdgcn_rcpf(x); }     // raw v_rcp_f32
DEV float siluf(float v) { return v * frcp(1.f + fexp2(-1.44269504f * v)); }
DEV float softplusf(float v) {
  return fmaxf(v, 0.f) + 0.69314718f * flog2(1.f + fexp2(-1.44269504f * fabsf(v)));
}

DEV float wredx(float v) {
#pragma unroll
  for (int o = 1; o < 64; o <<= 1) v += __shfl_xor(v, o);
  return v;
}

// DPP / swizzle cross-lane helpers (VALU-pipe DPP where possible)
#define DPPF(v, ctrl) __uint_as_float((uint)__builtin_amdgcn_mov_dpp((int)__float_as_uint(v), (ctrl), 0xf, 0xf, true))
#define SWZF(v, pat) __uint_as_float((uint)__builtin_amdgcn_ds_swizzle((int)__float_as_uint(v), (pat)))

DEV void gload_lds16(const void* g, void* l) {
  __builtin_amdgcn_global_load_lds(
      (const __attribute__((address_space(1))) uint32_t*)(uintptr_t)g,
      (__attribute__((address_space(3))) uint32_t*)(uint32_t)(uintptr_t)l,
      16, 0, 0);
}

// ---------------- front end ----------------

// x (B,T,65) -> hpbf (B,T,128) = silu(pointconv), bf16
__global__ void front_pointconv(const float* __restrict__ x, const float* __restrict__ pw,
                                const float* __restrict__ pb, __hip_bfloat16* __restrict__ hpbf) {
  int t = blockIdx.x, b = blockIdx.y, c = threadIdx.x;  // 128 threads
  __shared__ float xs[64];
  if (c < 64) xs[c] = x[((size_t)b * T + t) * 65 + c];
  __syncthreads();
  float acc = pb[c];
  const float4* pwr = (const float4*)(pw + c * 64);
#pragma unroll
  for (int i = 0; i < 16; ++i) {
    float4 w4 = pwr[i];
    acc = fmaf(w4.x, xs[4 * i + 0], acc);
    acc = fmaf(w4.y, xs[4 * i + 1], acc);
    acc = fmaf(w4.z, xs[4 * i + 2], acc);
    acc = fmaf(w4.w, xs[4 * i + 3], acc);
  }
  hpbf[((size_t)b * T + t) * 128 + c] = __float2bfloat16(siluf(acc));
}

// hpbf (B,T,128) -> Xim (BT, 3456) bf16, col j*128+ci = hpbf[b, t-13+j, ci]
__global__ void im2col_front(const __hip_bfloat16* __restrict__ hpbf,
                             __hip_bfloat16* __restrict__ Xim) {
  int idx = blockIdx.x * 256 + threadIdx.x;  // BT*432 threads, 16B each
  if (idx >= BT * 432) return;
  int row = idx / 432, r = idx - row * 432;
  int j = r >> 4, seg = r & 15;
  int b = row >> 9, t = row & 511;
  int ts = t - 13 + j;
  uint4 v = {0u, 0u, 0u, 0u};
  if (ts >= 0 && ts < T) v = *(const uint4*)(hpbf + ((size_t)(b * T + ts)) * 128 + seg * 8);
  *(uint4*)(Xim + (size_t)row * KCONV + j * 128 + seg * 8) = v;
}

// c1w(256,128,3), c2w(256,128,9), c3w(256,128,27) -> Wfr(768, 3456) bf16
__global__ void build_conv_w(const float* __restrict__ c1w, const float* __restrict__ c2w,
                             const float* __restrict__ c3w, __hip_bfloat16* __restrict__ Wfr) {
  int total = NCONV * KCONV;
  for (int idx = blockIdx.x * 256 + threadIdx.x; idx < total; idx += gridDim.x * 256) {
    int co = idx / KCONV, r = idx - co * KCONV;
    int j = r >> 7, ci = r & 127;
    float v = 0.f;
    if (co < 256) {
      int k = j - 12;
      if (k >= 0 && k < 3) v = c1w[((size_t)co * 128 + ci) * 3 + k];
    } else if (co < 512) {
      int k = j - 9;
      if (k >= 0 && k < 9) v = c2w[((size_t)(co - 256) * 128 + ci) * 9 + k];
    } else {
      v = c3w[((size_t)(co - 512) * 128 + ci) * 27 + j];
    }
    Wfr[idx] = __float2bfloat16(v);
  }
}

__global__ void build_conv_b(const float* __restrict__ b1, const float* __restrict__ b2,
                             const float* __restrict__ b3, float* __restrict__ cb) {
  int i = blockIdx.x * 256 + threadIdx.x;
  if (i >= NCONV) return;
  cb[i] = (i < 256) ? b1[i] : (i < 512) ? b2[i - 256] : b3[i - 512];
}

// ---------------- helpers ----------------

// f32 (N,K) -> bf16 (Npad,Kpad) zero-padded
__global__ void cvt_pad(const float* __restrict__ src, __hip_bfloat16* __restrict__ dst,
                        int N, int K, int Npad, int Kpad) {
  int total = Npad * Kpad;
  for (int idx = blockIdx.x * 256 + threadIdx.x; idx < total; idx += gridDim.x * 256) {
    int n = idx / Kpad, k = idx - n * Kpad;
    float v = (n < N && k < K) ? src[(size_t)n * K + k] : 0.f;
    dst[idx] = __float2bfloat16(v);
  }
}

__global__ void zero_pad_cols(__hip_bfloat16* __restrict__ buf, int rows, int ld, int c0) {
  int w = ld - c0;
  int total = rows * w;
  int idx = blockIdx.x * 256 + threadIdx.x;
  if (idx < total) buf[(size_t)(idx / w) * ld + c0 + (idx % w)] = __float2bfloat16(0.f);
}

// rmsnorm row (769) -> bf16 padded row (832)
__global__ __launch_bounds__(256) void rmsnorm_bf(const float* __restrict__ h,
                                                  const float* __restrict__ w,
                                                  __hip_bfloat16* __restrict__ ubf) {
  int row = blockIdx.x;
  const float* hr = h + (size_t)row * D_MODEL;
  __shared__ float red[4];
  int wid = threadIdx.x >> 6, lane = threadIdx.x & 63;
  float ss = 0.f;
  for (int i = threadIdx.x; i < D_MODEL; i += 256) { float v = hr[i]; ss = fmaf(v, v, ss); }
  ss = wredx(ss);
  if (lane == 0) red[wid] = ss;
  __syncthreads();
  float tot = red[0] + red[1] + red[2] + red[3];
  float sc = rsqrtf(tot * (1.f / D_MODEL) + 1e-6f);
  for (int i = threadIdx.x; i < KP_MODEL; i += 256) {
    float v = (i < D_MODEL) ? hr[i] * sc * w[i] : 0.f;
    ubf[(size_t)row * KP_MODEL + i] = __float2bfloat16(v);
  }
}

// ---------------- bf16 MFMA GEMM:  C[m][n] = sum_k A[m][k] * W[n][k] (+ epilogue) ----------------
// EPI 0: plain f32; 1: softplus(acc+bias[n]) -> dtdu float2 {dt, dt*du} in (b,t,d);
// 6: split-K raw partial store; 7: bf16 store to auxb[m*ldc+n]
template <int EPI>
__global__ __launch_bounds__(256) void gemm_bf16(const __hip_bfloat16* __restrict__ A,
                                                 const __hip_bfloat16* __restrict__ W,
                                                 float* __restrict__ C, int M, int Nreal, int Kp,
                                                 const float* extra, int ldadd, int ldc,
                                                 float2* auxv, __hip_bfloat16* auxb,
                                                 const __hip_bfloat16* auxr) {
  __shared__ __align__(16) __hip_bfloat16 As[128 * 64];
  __shared__ __align__(16) __hip_bfloat16 Bs[128 * 64];
  const int tid = threadIdx.x;
  const int wid = tid >> 6, lane = tid & 63;
  const int wr = wid >> 1, wc = wid & 1;
  const int m0 = blockIdx.y * 128, n0 = blockIdx.x * 128;
  f32x4 acc[4][4] = {};
  const int lrow = lane >> 3;                                 // row within 8-row segment
  const int cbyte = ((lane & 7) << 4) ^ (lrow << 4);          // inverse-swizzled source col byte
  const char* Ab = (const char*)A;
  const char* Wb = (const char*)W;
  const size_t strideAB = (size_t)Kp * 2;
  const int swz = (lane & 7) << 4;

  int kbeg = 0, kend = Kp;
  if constexpr (EPI == 6) {
    int khalf = (((Kp >> 1) + 63) >> 6) << 6;
    if (blockIdx.z == 0) kend = khalf; else kbeg = khalf;
  }

  for (int k0 = kbeg; k0 < kend; k0 += 64) {
#pragma unroll
    for (int i = 0; i < 4; ++i) {
      int seg = i * 4 + wid;                                  // wave-uniform
      int row = seg * 8 + lrow;
      gload_lds16(Ab + (size_t)(m0 + row) * strideAB + k0 * 2 + cbyte, (char*)As + seg * 1024);
      gload_lds16(Wb + (size_t)(n0 + row) * strideAB + k0 * 2 + cbyte, (char*)Bs + seg * 1024);
    }
    __syncthreads();
#pragma unroll
    for (int kk = 0; kk < 2; ++kk) {
      int kb = kk * 64 + ((lane >> 4) << 4);                  // byte offset of this lane's 8 bf16
      bf16x8v af[4], bfr[4];
#pragma unroll
      for (int mi = 0; mi < 4; ++mi) {
        int row = wr * 64 + mi * 16 + (lane & 15);
        af[mi] = *(const bf16x8v*)((const char*)As + row * 128 + (kb ^ swz));
      }
#pragma unroll
      for (int ni = 0; ni < 4; ++ni) {
        int row = wc * 64 + ni * 16 + (lane & 15);
        bfr[ni] = *(const bf16x8v*)((const char*)Bs + row * 128 + (kb ^ swz));
      }
#pragma unroll
      for (int mi = 0; mi < 4; ++mi)
#pragma unroll
        for (int ni = 0; ni < 4; ++ni)
          acc[mi][ni] = __builtin_amdgcn_mfma_f32_16x16x32_bf16(af[mi], bfr[ni], acc[mi][ni], 0, 0, 0);
    }
    __syncthreads();
  }

#pragma unroll
  for (int mi = 0; mi < 4; ++mi) {
#pragma unroll
    for (int ni = 0; ni < 4; ++ni) {
      int n = n0 + wc * 64 + ni * 16 + (lane & 15);
      if (n < Nreal) {
        int mb = m0 + wr * 64 + mi * 16 + ((lane >> 4) << 2);
#pragma unroll
        for (int v = 0; v < 4; ++v) {
          float val = acc[mi][ni][v];
          int m = mb + v;
          if constexpr (EPI == 1) {
            val = softplusf(val + extra[n]);
            float du = __bfloat162float(auxr[(size_t)m * KP_INNER + n]);
            auxv[(size_t)m * D_INNER + n] = make_float2(val, val * du);   // (b,t,d) coalesced
          } else if constexpr (EPI == 6) {
            C[((size_t)blockIdx.z * M + m) * ldc + n] = val;
          } else if constexpr (EPI == 7) {
            auxb[(size_t)m * ldc + n] = __float2bfloat16(val);
          } else {
            C[(size_t)m * ldc + n] = val;
          }
        }
      }
    }
  }
}

// ---------------- split-K combine kernels ----------------
// conv combine + silu + pe fill (covers full D_MODEL row)
__global__ void combine_conv(const float* __restrict__ p, const float* __restrict__ cb,
                             const float* __restrict__ x, float* __restrict__ h) {
  int i = blockIdx.x * 256 + threadIdx.x;
  if (i >= BT * D_MODEL) return;
  int m = i / D_MODEL, n = i - m * D_MODEL;
  float v;
  if (n < NCONV) {
    v = siluf(p[(size_t)m * NCONV + n] + p[(size_t)BT * NCONV + (size_t)m * NCONV + n] + cb[n]);
  } else {
    v = x[(size_t)m * 65 + 64];
  }
  h[i] = v;
}

// x_proj combine: parts (2, BT, 256) -> dtbf (BT,64) bf16 + bcbf (BT,64) packed {B,C} bf16x2
__global__ void combine_xproj(const float* __restrict__ p, __hip_bfloat16* __restrict__ dtbf,
                              __hip_bfloat16* __restrict__ bcb) {
  int i = blockIdx.x * 256 + threadIdx.x;
  if (i >= BT * 192) return;
  int m = i / 192, n = i - m * 192;
  if (n >= DT_RANK + 2 * D_STATE) return;
  float v = p[(size_t)m * 256 + n] + p[(size_t)(BT + m) * 256 + n];
  if (n < 64) dtbf[(size_t)m * 64 + n] = __float2bfloat16(n < DT_RANK ? v : 0.f);
  if (n >= DT_RANK && n < DT_RANK + D_STATE)
    bcb[((size_t)m * 64 + (n - DT_RANK)) * 2] = __float2bfloat16(v);          // B -> lo
  else if (n >= DT_RANK + D_STATE)
    bcb[((size_t)m * 64 + (n - DT_RANK - D_STATE)) * 2 + 1] = __float2bfloat16(v);  // C -> hi
}

__global__ void combine_out(const float* __restrict__ p, float* __restrict__ h) {
  int i = blockIdx.x * 256 + threadIdx.x;
  if (i >= BT * D_MODEL) return;
  h[i] += p[i] + p[(size_t)BT * D_MODEL + i];
}

// ---------------- depthwise causal conv (k=4) + silu -> bf16 only ----------------
__global__ void dwconv_silu(const __hip_bfloat16* __restrict__ xz, const float* __restrict__ cw,
                            const float* __restrict__ cb, __hip_bfloat16* __restrict__ xinbf) {
  int idx = blockIdx.x * 256 + threadIdx.x;
  if (idx >= BT * D_INNER) return;
  int bt = idx / D_INNER;
  int d = idx - bt * D_INNER;
  int t = bt & (T - 1);
  float acc = cb[d];
  const __hip_bfloat16* col = xz + (size_t)bt * D2 + d;
#pragma unroll
  for (int k = 0; k < 4; ++k) {
    int tt = t + k - 3;
    float v = (tt >= 0) ? __bfloat162float(col[(ptrdiff_t)(k - 3) * D2]) : 0.f;
    acc = fmaf(cw[d * 4 + k], v, acc);
  }
  acc = siluf(acc);
  xinbf[(size_t)bt * KP_INNER + d] = __float2bfloat16(acc);
}

// ---------------- fused single-pass scan, LDS-staged, double-buffered ----------------
// block = 1024 threads = 16 waves = 16 consecutive d, one b; wave walks full T=512 in
// 8 chunks of 64 t. Chunk c+1 staged while computing chunk c; one barrier per chunk.
// bc: global coalesced register ping-pong (no copy insts). Reduce: DPP folds + 3 DS ops;
// fold order (xor1,xor2,xor4) -> slot = brl (bit-reverse of lane&7).

#define FCOMP(REG, T0L, T0G)                                                 \
  {                                                                          \
    float4 q0 = *(const float4*)&dtsS[(T0L)];                                \
    float4 q1 = *(const float4*)&dtsS[(T0L) + 4];                            \
    float4 u0 = *(const float4*)&dtusS[(T0L)];                               \
    float4 u1 = *(const float4*)&dtusS[(T0L) + 4];                           \
    float dtv[8] = {q0.x, q0.y, q0.z, q0.w, q1.x, q1.y, q1.z, q1.w};         \
    float duv[8] = {u0.x, u0.y, u0.z, u0.w, u1.x, u1.y, u1.z, u1.w};         \
    float vv[8];                                                             \
    _Pragma("unroll") for (int k = 0; k < 8; ++k) {                          \
      float Bv = __uint_as_float(REG[k] << 16);                              \
      float Cv = __uint_as_float(REG[k] & 0xffff0000u);                      \
      h = fmaf(fexp2(dtv[k] * a2), h, duv[k] * Bv);                          \
      vv[k] = h * Cv;                                                        \
    }                                                                        \
    _Pragma("unroll") for (int k = 0; k < 4; ++k) {                          \
      float snd = bb0 ? vv[k] : vv[k + 4];                                   \
      float kp = bb0 ? vv[k + 4] : vv[k];                                    \
      vv[k] = kp + DPPF(snd, 0xB1);                                          \
    }                                                                        \
    _Pragma("unroll") for (int k = 0; k < 2; ++k) {                          \
      float snd = bb1 ? vv[k] : vv[k + 2];                                   \
      float kp = bb1 ? vv[k + 2] : vv[k];                                    \
      vv[k] = kp + DPPF(snd, 0x4E);                                          \
    }                                                                        \
    {                                                                        \
      float snd = bb2 ? vv[0] : vv[1];                                       \
      float kp = bb2 ? vv[1] : vv[0];                                        \
      vv[0] = kp + SWZF(snd, 0x101F);                                        \
    }                                                                        \
    float y = vv[0];                                                         \
    y += DPPF(y, 0x128);                                                     \
    y += SWZF(y, 0x401F);                                                    \
    y += __shfl_xor(y, 32);                                                  \
    if (lane < 8 && valid) {                                                 \
      float du_ = xinS[((T0L) + brl) * 17 + wid];                            \
      float zv = xzS[((T0L) + brl) * 17 + wid];                              \
      float yo = (y + du_ * dsk) * siluf(zv);                                \
      ybf[(rb + (T0G) + brl) * KP_INNER + d] = __float2bfloat16(yo);         \
    }                                                                        \
  }

__global__ __launch_bounds__(1024) void scan_fused(const uint* __restrict__ bcp16,
                                                   const float2* __restrict__ dtdu,
                                                   const __hip_bfloat16* __restrict__ xinbf,
                                                   const __hip_bfloat16* __restrict__ xzbf,
                                                   const float* __restrict__ A_log,
                                                   const float* __restrict__ Dskip,
                                                   __hip_bfloat16* __restrict__ ybf) {
  __shared__ __align__(16) float dts[2][16 * 68];
  __shared__ __align__(16) float dtus[2][16 * 68];
  __shared__ float xins[2][CHT * 17];
  __shared__ float xzs[2][CHT * 17];
  int tid = threadIdx.x, wid = tid >> 6, lane = tid & 63;
  int dg = blockIdx.x % DGRP, b = blockIdx.x / DGRP;
  int d0 = dg * 16, d = d0 + wid;
  bool valid = (d < D_INNER);
  int dc = valid ? d : (D_INNER - 1);
  const size_t rb = (size_t)b * T;

  // staging coords: one element per thread per buffer (64 t x 16 d)
  int stt = tid >> 4, sdd = tid & 15;
  const float2* dsrc0 = dtdu + (rb + stt) * D_INNER + d0 + sdd;
  const __hip_bfloat16* xsrc0 = xinbf + (rb + stt) * KP_INNER + d0 + sdd;
  const __hip_bfloat16* zsrc0 = xzbf + (rb + stt) * D2 + D_INNER + d0 + sdd;
  auto stage = [&](int c, int s) {
    float2 dq = dsrc0[(size_t)c * CHT * D_INNER];
    dts[s][sdd * 68 + stt] = dq.x;
    dtus[s][sdd * 68 + stt] = dq.y;
    xins[s][stt * 17 + sdd] = __bfloat162float(xsrc0[(size_t)c * CHT * KP_INNER]);
    xzs[s][stt * 17 + sdd] = __bfloat162float(zsrc0[(size_t)c * CHT * D2]);
  };

  stage(0, 0);

  const bool bb2 = lane & 4, bb1 = lane & 2, bb0 = lane & 1;
  const int brl = ((lane & 1) << 2) | (lane & 2) | ((lane & 4) >> 2);
  float a2 = -__expf(A_log[(size_t)dc * D_STATE + lane]) * 1.44269504f;
  float dsk = Dskip[dc];
  float h = 0.f;
  const uint* bgp = bcp16 + rb * 64 + lane;

  __syncthreads();

  uint bA[8], bB[8];
#pragma unroll
  for (int k = 0; k < 8; ++k) bA[k] = bgp[k * 64];

  for (int ch = 0; ch < NCH; ++ch) {
    int s = ch & 1;
    const float* dtsS = &dts[s][wid * 68];
    const float* dtusS = &dtus[s][wid * 68];
    const float* xinS = &xins[s][0];
    const float* xzS = &xzs[s][0];
    if (ch + 1 < NCH) stage(ch + 1, s ^ 1);
    const uint* bp = bgp + (size_t)ch * CHT * 64;
#pragma unroll
    for (int gi = 0; gi < 4; ++gi) {
      int t0l = gi * 16;
      int t0g = ch * CHT + t0l;
#pragma unroll
      for (int k = 0; k < 8; ++k) bB[k] = bp[(t0l + 8 + k) * 64];
      FCOMP(bA, t0l, t0g);
      if (!(ch == NCH - 1 && gi == 3)) {
#pragma unroll
        for (int k = 0; k < 8; ++k) bA[k] = bp[(t0l + 16 + k) * 64];
      }
      FCOMP(bB, t0l + 8, t0g + 8);
    }
    __syncthreads();
  }
}

// ---------------- final layernorm + classifier ----------------
__global__ __launch_bounds__(256) void ln_head(const float* __restrict__ h,
                                               const float* __restrict__ lnw,
                                               const float* __restrict__ lnb,
                                               const float* __restrict__ ow,
                                               const float* __restrict__ ob,
                                               float* __restrict__ out) {
  int row = blockIdx.x;
  const float* hr = h + (size_t)row * D_MODEL;
  __shared__ float sh[D_MODEL];
  __shared__ float red[4];
  int wid = threadIdx.x >> 6, lane = threadIdx.x & 63;
  float s = 0.f;
  for (int i = threadIdx.x; i < D_MODEL; i += 256) { float v = hr[i]; sh[i] = v; s += v; }
  s = wredx(s);
  if (lane == 0) red[wid] = s;
  __syncthreads();
  float mean = (red[0] + red[1] + red[2] + red[3]) * (1.f / D_MODEL);
  __syncthreads();
  float vs = 0.f;
  for (int i = threadIdx.x; i < D_MODEL; i += 256) { float dd = sh[i] - mean; vs = fmaf(dd, dd, vs); }
  vs = wredx(vs);
  if (lane == 0) red[wid] = vs;
  __syncthreads();
  float var = (red[0] + red[1] + red[2] + red[3]) * (1.f / D_MODEL);
  float inv = rsqrtf(var + 1e-5f);
  for (int i = threadIdx.x; i < D_MODEL; i += 256)
    sh[i] = (sh[i] - mean) * inv * lnw[i] + lnb[i];
  __syncthreads();
  for (int c = wid; c < 10; c += 4) {
    float acc = 0.f;
    for (int i = lane; i < D_MODEL; i += 64) acc = fmaf(sh[i], ow[(size_t)c * D_MODEL + i], acc);
    acc = wredx(acc);
    if (lane == 0) out[(size_t)row * 10 + c] = acc + ob[c];
  }
}

// ---------------- launcher ----------------
extern "C" void kernel_launch(void* const* d_in, const int* in_sizes, int n_in,
                              void* d_out, int out_size, void* d_ws, size_t ws_size,
                              hipStream_t stream) {
  const float* x    = (const float*)d_in[0];
  const float* pcw  = (const float*)d_in[1];
  const float* pcb  = (const float*)d_in[2];
  const float* c1w  = (const float*)d_in[3];
  const float* c1b  = (const float*)d_in[4];
  const float* c2w  = (const float*)d_in[5];
  const float* c2b  = (const float*)d_in[6];
  const float* c3w  = (const float*)d_in[7];
  const float* c3b  = (const float*)d_in[8];
  const float* lnw  = (const float*)d_in[9];
  const float* lnb  = (const float*)d_in[10];
  const float* ow   = (const float*)d_in[11];
  const float* ob   = (const float*)d_in[12];
  const float* rmsw = (const float*)d_in[13];
  const float* Wi   = (const float*)d_in[14];
  const float* dww  = (const float*)d_in[15];
  const float* dwb  = (const float*)d_in[16];
  const float* Wx   = (const float*)d_in[17];
  const float* Wdt  = (const float*)d_in[18];
  const float* dtbv = (const float*)d_in[19];
  const float* Alog = (const float*)d_in[20];
  const float* Dsk  = (const float*)d_in[21];
  const float* Wo   = (const float*)d_in[22];
  float* out = (float*)d_out;

  char* w = (char*)d_ws;
  auto alloc = [&](size_t n) { char* p = w; w += (n + 255) & ~(size_t)255; return p; };
  // shared region: front-end buffers (dead after front GEMM) aliased with scan temps
  constexpr size_t REGION = 26400000;
  char* region = alloc(REGION);
  __hip_bfloat16* hpbf = (__hip_bfloat16*)region;                    // 524,288 B
  __hip_bfloat16* Xim  = (__hip_bfloat16*)(region + 600064);         // 14,155,776 B
  __hip_bfloat16* Wfr  = (__hip_bfloat16*)(region + 14755840 + 256); // 5,308,416 B
  float* cb768         = (float*)(region + 20065024);                // 3,072 B
  float2* dtduT        = (float2*)region;                            // 25,198,592 B (layer phase)
  __hip_bfloat16* bcbf = (__hip_bfloat16*)(region + 25198592);       // 524,288 B packed {B,C}

  float* hbuf          = (float*)alloc((size_t)BT * D_MODEL * 4);
  __hip_bfloat16* ubf  = (__hip_bfloat16*)alloc((size_t)BT * KP_MODEL * 2);
  __hip_bfloat16* xzbf = (__hip_bfloat16*)alloc((size_t)BT * D2 * 2);
  __hip_bfloat16* xinbf= (__hip_bfloat16*)alloc((size_t)BT * KP_INNER * 2);
  __hip_bfloat16* dtbf = (__hip_bfloat16*)alloc((size_t)BT * KP_DT * 2);
  __hip_bfloat16* ybf  = (__hip_bfloat16*)alloc((size_t)BT * KP_INNER * 2);
  __hip_bfloat16* Wibf = (__hip_bfloat16*)alloc((size_t)NP_IN * KP_MODEL * 2);
  __hip_bfloat16* Wxbf = (__hip_bfloat16*)alloc((size_t)NP_X * KP_INNER * 2);
  __hip_bfloat16* Wdtbf= (__hip_bfloat16*)alloc((size_t)NP_DT * KP_DT * 2);
  __hip_bfloat16* Wobf = (__hip_bfloat16*)alloc((size_t)NP_OUT * KP_INNER * 2);
  float* parts         = (float*)alloc((size_t)2 * BT * D_MODEL * 4);          // 12.6 MB split-K partials

  front_pointconv<<<dim3(T, B), 128, 0, stream>>>(x, pcw, pcb, hpbf);
  im2col_front<<<(BT * 432) / 256, 256, 0, stream>>>(hpbf, Xim);
  build_conv_w<<<2048, 256, 0, stream>>>(c1w, c2w, c3w, Wfr);
  build_conv_b<<<3, 256, 0, stream>>>(c1b, c2b, c3b, cb768);
  gemm_bf16<6><<<dim3(NCONV / 128, BT / 128, 2), 256, 0, stream>>>(Xim, Wfr, parts, BT, NCONV, KCONV,
                                                                   nullptr, 0, NCONV,
                                                                   nullptr, nullptr, nullptr);
  combine_conv<<<(BT * D_MODEL + 255) / 256, 256, 0, stream>>>(parts, cb768, x, hbuf);
  // pad columns written once (scan/dwconv never touch cols >= D_INNER)
  zero_pad_cols<<<(BT * (KP_INNER - D_INNER) + 255) / 256, 256, 0, stream>>>(xinbf, BT, KP_INNER, D_INNER);
  zero_pad_cols<<<(BT * (KP_INNER - D_INNER) + 255) / 256, 256, 0, stream>>>(ybf, BT, KP_INNER, D_INNER);

  for (int l = 0; l < NLAYER; ++l) {
    const float* Al = Alog + (size_t)l * D_INNER * D_STATE;
    cvt_pad<<<2048, 256, 0, stream>>>(Wi + (size_t)l * D2 * D_MODEL, Wibf, D2, D_MODEL, NP_IN, KP_MODEL);
    cvt_pad<<<512, 256, 0, stream>>>(Wx + (size_t)l * (DT_RANK + 2 * D_STATE) * D_INNER, Wxbf,
                                     DT_RANK + 2 * D_STATE, D_INNER, NP_X, KP_INNER);
    cvt_pad<<<256, 256, 0, stream>>>(Wdt + (size_t)l * D_INNER * DT_RANK, Wdtbf, D_INNER, DT_RANK, NP_DT, KP_DT);
    cvt_pad<<<1024, 256, 0, stream>>>(Wo + (size_t)l * D_MODEL * D_INNER, Wobf, D_MODEL, D_INNER, NP_OUT, KP_INNER);

    rmsnorm_bf<<<BT, 256, 0, stream>>>(hbuf, rmsw + (size_t)l * D_MODEL, ubf);
    gemm_bf16<7><<<dim3(NP_IN / 128, BT / 128), 256, 0, stream>>>(ubf, Wibf, nullptr, BT, D2, KP_MODEL,
                                                                  nullptr, 0, D2,
                                                                  nullptr, xzbf, nullptr);
    dwconv_silu<<<(BT * D_INNER + 255) / 256, 256, 0, stream>>>(xzbf, dww + (size_t)l * D_INNER * 4,
                                                                dwb + (size_t)l * D_INNER, xinbf);
    gemm_bf16<6><<<dim3(NP_X / 128, BT / 128, 2), 256, 0, stream>>>(xinbf, Wxbf, parts, BT,
                                                                    DT_RANK + 2 * D_STATE, KP_INNER,
                                                                    nullptr, 0, 256,
                                                                    nullptr, nullptr, nullptr);
    combine_xproj<<<(BT * 192 + 255) / 256, 256, 0, stream>>>(parts, dtbf, bcbf);
    gemm_bf16<1><<<dim3(NP_DT / 128, BT / 128), 256, 0, stream>>>(dtbf, Wdtbf, nullptr, BT, D_INNER, KP_DT,
                                                                  dtbv + (size_t)l * D_INNER, 0, 0,
                                                                  dtduT, nullptr, xinbf);
    scan_fused<<<dim3(B * DGRP), 1024, 0, stream>>>((const uint*)bcbf, dtduT, xinbf, xzbf, Al,
                                                    Dsk + (size_t)l * D_INNER, ybf);
    gemm_bf16<6><<<dim3(NP_OUT / 128, BT / 128, 2), 256, 0, stream>>>(ybf, Wobf, parts, BT, D_MODEL, KP_INNER,
                                                                      nullptr, 0, D_MODEL,
                                                                      nullptr, nullptr, nullptr);
    combine_out<<<(BT * D_MODEL + 255) / 256, 256, 0, stream>>>(parts, hbuf);
  }
  ln_head<<<BT, 256, 0, stream>>>(hbuf, lnw, lnb, ow, ob, out);
}

// Round 14
// 499.367 us; speedup vs baseline: 1.5395x; 1.1108x over previous
//
#include <hip/hip_runtime.h>
#include <hip/hip_bf16.h>
#include <cstdint>
#include <math.h>

#define DEV static __device__ __forceinline__

typedef __attribute__((ext_vector_type(8))) __bf16 bf16x8v;
typedef __attribute__((ext_vector_type(4))) float f32x4;

constexpr int B = 4, T = 512, BT = B * T;
constexpr int D_MODEL = 769, D_INNER = 1538, D2 = 3076;
constexpr int DT_RANK = 49, D_STATE = 64;
constexpr int NCH = 8, CHT = 64;           // fused scan: 8 chunks x 64 t
constexpr int DGRP = (D_INNER + 15) / 16;  // 97 d-groups of 16
// padded GEMM dims (K multiple of 64, N multiple of 128)
constexpr int KP_MODEL = 832;   // 769
constexpr int KP_INNER = 1600;  // 1538
constexpr int KP_DT    = 64;    // 49
constexpr int NP_IN  = 3200;    // 3076
constexpr int NP_X   = 256;     // 177
constexpr int NP_DT  = 1664;    // 1538
constexpr int NP_OUT = 896;     // 769
constexpr int KCONV  = 3456;    // 27*128 unified front-conv reduction
constexpr int NCONV  = 768;

DEV float fexp2(float x) { return __builtin_amdgcn_exp2f(x); }   // raw v_exp_f32
DEV float flog2(float x) { return __builtin_amdgcn_logf(x); }    // raw v_log_f32
DEV float frcp(float x) { return __builtin_amdgcn_rcpf(x); }     // raw v_rcp_f32
DEV float siluf(float v) { return v * frcp(1.f + fexp2(-1.44269504f * v)); }
DEV float softplusf(float v) {
  return fmaxf(v, 0.f) + 0.69314718f * flog2(1.f + fexp2(-1.44269504f * fabsf(v)));
}

DEV float wredx(float v) {
#pragma unroll
  for (int o = 1; o < 64; o <<= 1) v += __shfl_xor(v, o);
  return v;
}

// DPP / swizzle cross-lane helpers (VALU-pipe DPP where possible)
#define DPPF(v, ctrl) __uint_as_float((uint)__builtin_amdgcn_mov_dpp((int)__float_as_uint(v), (ctrl), 0xf, 0xf, true))
#define SWZF(v, pat) __uint_as_float((uint)__builtin_amdgcn_ds_swizzle((int)__float_as_uint(v), (pat)))

DEV void gload_lds16(const void* g, void* l) {
  __builtin_amdgcn_global_load_lds(
      (const __attribute__((address_space(1))) uint32_t*)(uintptr_t)g,
      (__attribute__((address_space(3))) uint32_t*)(uint32_t)(uintptr_t)l,
      16, 0, 0);
}

// ---------------- front end ----------------

// x (B,T,65) -> hpbf (B,T,128) = silu(pointconv), bf16
__global__ void front_pointconv(const float* __restrict__ x, const float* __restrict__ pw,
                                const float* __restrict__ pb, __hip_bfloat16* __restrict__ hpbf) {
  int t = blockIdx.x, b = blockIdx.y, c = threadIdx.x;  // 128 threads
  __shared__ float xs[64];
  if (c < 64) xs[c] = x[((size_t)b * T + t) * 65 + c];
  __syncthreads();
  float acc = pb[c];
  const float4* pwr = (const float4*)(pw + c * 64);
#pragma unroll
  for (int i = 0; i < 16; ++i) {
    float4 w4 = pwr[i];
    acc = fmaf(w4.x, xs[4 * i + 0], acc);
    acc = fmaf(w4.y, xs[4 * i + 1], acc);
    acc = fmaf(w4.z, xs[4 * i + 2], acc);
    acc = fmaf(w4.w, xs[4 * i + 3], acc);
  }
  hpbf[((size_t)b * T + t) * 128 + c] = __float2bfloat16(siluf(acc));
}

// hpbf (B,T,128) -> Xim (BT, 3456) bf16, col j*128+ci = hpbf[b, t-13+j, ci]
__global__ void im2col_front(const __hip_bfloat16* __restrict__ hpbf,
                             __hip_bfloat16* __restrict__ Xim) {
  int idx = blockIdx.x * 256 + threadIdx.x;  // BT*432 threads, 16B each
  if (idx >= BT * 432) return;
  int row = idx / 432, r = idx - row * 432;
  int j = r >> 4, seg = r & 15;
  int b = row >> 9, t = row & 511;
  int ts = t - 13 + j;
  uint4 v = {0u, 0u, 0u, 0u};
  if (ts >= 0 && ts < T) v = *(const uint4*)(hpbf + ((size_t)(b * T + ts)) * 128 + seg * 8);
  *(uint4*)(Xim + (size_t)row * KCONV + j * 128 + seg * 8) = v;
}

// c1w/c2w/c3w -> Wfr(768, 3456) bf16; tail range fills bias vector
__global__ void build_conv_wb(const float* __restrict__ c1w, const float* __restrict__ c2w,
                              const float* __restrict__ c3w, const float* __restrict__ b1,
                              const float* __restrict__ b2, const float* __restrict__ b3,
                              __hip_bfloat16* __restrict__ Wfr, float* __restrict__ cb) {
  int total = NCONV * KCONV;
  for (int idx = blockIdx.x * 256 + threadIdx.x; idx < total + NCONV; idx += gridDim.x * 256) {
    if (idx < total) {
      int co = idx / KCONV, r = idx - co * KCONV;
      int j = r >> 7, ci = r & 127;
      float v = 0.f;
      if (co < 256) {
        int k = j - 12;
        if (k >= 0 && k < 3) v = c1w[((size_t)co * 128 + ci) * 3 + k];
      } else if (co < 512) {
        int k = j - 9;
        if (k >= 0 && k < 9) v = c2w[((size_t)(co - 256) * 128 + ci) * 9 + k];
      } else {
        v = c3w[((size_t)(co - 512) * 128 + ci) * 27 + j];
      }
      Wfr[idx] = __float2bfloat16(v);
    } else {
      int i = idx - total;
      cb[i] = (i < 256) ? b1[i] : (i < 512) ? b2[i - 256] : b3[i - 512];
    }
  }
}

// ---------------- weight conversion, all tensors both layers, 1 launch ----------------
__global__ void cvt_all(const float* __restrict__ Wi, const float* __restrict__ Wx,
                        const float* __restrict__ Wdt, const float* __restrict__ Wo,
                        __hip_bfloat16* __restrict__ Wibf, __hip_bfloat16* __restrict__ Wxbf,
                        __hip_bfloat16* __restrict__ Wdtbf, __hip_bfloat16* __restrict__ Wobf) {
  int l = blockIdx.y >> 2, t = blockIdx.y & 3;
  const float* src;
  __hip_bfloat16* dst;
  int N, K, Npad, Kpad;
  if (t == 0) { src = Wi + (size_t)l * D2 * D_MODEL; dst = Wibf + (size_t)l * NP_IN * KP_MODEL;
                N = D2; K = D_MODEL; Npad = NP_IN; Kpad = KP_MODEL; }
  else if (t == 1) { src = Wx + (size_t)l * (DT_RANK + 2 * D_STATE) * D_INNER;
                dst = Wxbf + (size_t)l * NP_X * KP_INNER;
                N = DT_RANK + 2 * D_STATE; K = D_INNER; Npad = NP_X; Kpad = KP_INNER; }
  else if (t == 2) { src = Wdt + (size_t)l * D_INNER * DT_RANK; dst = Wdtbf + (size_t)l * NP_DT * KP_DT;
                N = D_INNER; K = DT_RANK; Npad = NP_DT; Kpad = KP_DT; }
  else { src = Wo + (size_t)l * D_MODEL * D_INNER; dst = Wobf + (size_t)l * NP_OUT * KP_INNER;
                N = D_MODEL; K = D_INNER; Npad = NP_OUT; Kpad = KP_INNER; }
  int total = Npad * Kpad;
  for (int idx = blockIdx.x * 256 + threadIdx.x; idx < total; idx += gridDim.x * 256) {
    int n = idx / Kpad, k = idx - n * Kpad;
    float v = (n < N && k < K) ? src[(size_t)n * K + k] : 0.f;
    dst[idx] = __float2bfloat16(v);
  }
}

__global__ void zero_pad_cols(__hip_bfloat16* __restrict__ buf, int rows, int ld, int c0) {
  int w = ld - c0;
  int total = rows * w;
  int idx = blockIdx.x * 256 + threadIdx.x;
  if (idx < total) buf[(size_t)(idx / w) * ld + c0 + (idx % w)] = __float2bfloat16(0.f);
}

// ---------------- bf16 MFMA GEMM:  C[m][n] = sum_k A[m][k] * W[n][k] (+ epilogue) ----------------
// EPI 1: softplus(acc+bias[n]) -> dtdu float2 {dt, dt*du} in (b,t,d);
// 6: split-K raw partial store; 7: bf16 store to auxb[m*ldc+n]
template <int EPI>
__global__ __launch_bounds__(256) void gemm_bf16(const __hip_bfloat16* __restrict__ A,
                                                 const __hip_bfloat16* __restrict__ W,
                                                 float* __restrict__ C, int M, int Nreal, int Kp,
                                                 const float* extra, int ldadd, int ldc,
                                                 float2* auxv, __hip_bfloat16* auxb,
                                                 const __hip_bfloat16* auxr) {
  __shared__ __align__(16) __hip_bfloat16 As[128 * 64];
  __shared__ __align__(16) __hip_bfloat16 Bs[128 * 64];
  const int tid = threadIdx.x;
  const int wid = tid >> 6, lane = tid & 63;
  const int wr = wid >> 1, wc = wid & 1;
  const int m0 = blockIdx.y * 128, n0 = blockIdx.x * 128;
  f32x4 acc[4][4] = {};
  const int lrow = lane >> 3;                                 // row within 8-row segment
  const int cbyte = ((lane & 7) << 4) ^ (lrow << 4);          // inverse-swizzled source col byte
  const char* Ab = (const char*)A;
  const char* Wb = (const char*)W;
  const size_t strideAB = (size_t)Kp * 2;
  const int swz = (lane & 7) << 4;

  int kbeg = 0, kend = Kp;
  if constexpr (EPI == 6) {
    int khalf = (((Kp >> 1) + 63) >> 6) << 6;
    if (blockIdx.z == 0) kend = khalf; else kbeg = khalf;
  }

  for (int k0 = kbeg; k0 < kend; k0 += 64) {
#pragma unroll
    for (int i = 0; i < 4; ++i) {
      int seg = i * 4 + wid;                                  // wave-uniform
      int row = seg * 8 + lrow;
      gload_lds16(Ab + (size_t)(m0 + row) * strideAB + k0 * 2 + cbyte, (char*)As + seg * 1024);
      gload_lds16(Wb + (size_t)(n0 + row) * strideAB + k0 * 2 + cbyte, (char*)Bs + seg * 1024);
    }
    __syncthreads();
#pragma unroll
    for (int kk = 0; kk < 2; ++kk) {
      int kb = kk * 64 + ((lane >> 4) << 4);                  // byte offset of this lane's 8 bf16
      bf16x8v af[4], bfr[4];
#pragma unroll
      for (int mi = 0; mi < 4; ++mi) {
        int row = wr * 64 + mi * 16 + (lane & 15);
        af[mi] = *(const bf16x8v*)((const char*)As + row * 128 + (kb ^ swz));
      }
#pragma unroll
      for (int ni = 0; ni < 4; ++ni) {
        int row = wc * 64 + ni * 16 + (lane & 15);
        bfr[ni] = *(const bf16x8v*)((const char*)Bs + row * 128 + (kb ^ swz));
      }
#pragma unroll
      for (int mi = 0; mi < 4; ++mi)
#pragma unroll
        for (int ni = 0; ni < 4; ++ni)
          acc[mi][ni] = __builtin_amdgcn_mfma_f32_16x16x32_bf16(af[mi], bfr[ni], acc[mi][ni], 0, 0, 0);
    }
    __syncthreads();
  }

#pragma unroll
  for (int mi = 0; mi < 4; ++mi) {
#pragma unroll
    for (int ni = 0; ni < 4; ++ni) {
      int n = n0 + wc * 64 + ni * 16 + (lane & 15);
      if (n < Nreal) {
        int mb = m0 + wr * 64 + mi * 16 + ((lane >> 4) << 2);
#pragma unroll
        for (int v = 0; v < 4; ++v) {
          float val = acc[mi][ni][v];
          int m = mb + v;
          if constexpr (EPI == 1) {
            val = softplusf(val + extra[n]);
            float du = __bfloat162float(auxr[(size_t)m * KP_INNER + n]);
            auxv[(size_t)m * D_INNER + n] = make_float2(val, val * du);   // (b,t,d) coalesced
          } else if constexpr (EPI == 6) {
            C[((size_t)blockIdx.z * M + m) * ldc + n] = val;
          } else if constexpr (EPI == 7) {
            auxb[(size_t)m * ldc + n] = __float2bfloat16(val);
          } else {
            C[(size_t)m * ldc + n] = val;
          }
        }
      }
    }
  }
}

// ---------------- fused combine kernels (block per row) ----------------
// front conv combine + silu + pe + rmsnorm -> hbuf, ubf
__global__ __launch_bounds__(256) void combine_conv_rms(const float* __restrict__ p,
                                                        const float* __restrict__ cb,
                                                        const float* __restrict__ x,
                                                        const float* __restrict__ rmsw,
                                                        float* __restrict__ h,
                                                        __hip_bfloat16* __restrict__ ubf) {
  int m = blockIdx.x;
  __shared__ float sh[D_MODEL];
  __shared__ float red[4];
  int wid = threadIdx.x >> 6, lane = threadIdx.x & 63;
  float ss = 0.f;
  for (int n = threadIdx.x; n < D_MODEL; n += 256) {
    float v;
    if (n < NCONV)
      v = siluf(p[(size_t)m * NCONV + n] + p[(size_t)BT * NCONV + (size_t)m * NCONV + n] + cb[n]);
    else
      v = x[(size_t)m * 65 + 64];
    sh[n] = v;
    h[(size_t)m * D_MODEL + n] = v;
    ss = fmaf(v, v, ss);
  }
  ss = wredx(ss);
  if (lane == 0) red[wid] = ss;
  __syncthreads();
  float sc = rsqrtf((red[0] + red[1] + red[2] + red[3]) * (1.f / D_MODEL) + 1e-6f);
  for (int i = threadIdx.x; i < KP_MODEL; i += 256) {
    float v = (i < D_MODEL) ? sh[i] * sc * rmsw[i] : 0.f;
    ubf[(size_t)m * KP_MODEL + i] = __float2bfloat16(v);
  }
}

// out_proj combine + residual + rmsnorm(next layer) -> hbuf, ubf
__global__ __launch_bounds__(256) void combine_out_rms(const float* __restrict__ p,
                                                       const float* __restrict__ rmsw,
                                                       float* __restrict__ h,
                                                       __hip_bfloat16* __restrict__ ubf) {
  int m = blockIdx.x;
  __shared__ float sh[D_MODEL];
  __shared__ float red[4];
  int wid = threadIdx.x >> 6, lane = threadIdx.x & 63;
  float ss = 0.f;
  for (int n = threadIdx.x; n < D_MODEL; n += 256) {
    size_t i = (size_t)m * D_MODEL + n;
    float v = h[i] + p[i] + p[(size_t)BT * D_MODEL + i];
    sh[n] = v;
    h[i] = v;
    ss = fmaf(v, v, ss);
  }
  ss = wredx(ss);
  if (lane == 0) red[wid] = ss;
  __syncthreads();
  float sc = rsqrtf((red[0] + red[1] + red[2] + red[3]) * (1.f / D_MODEL) + 1e-6f);
  for (int i = threadIdx.x; i < KP_MODEL; i += 256) {
    float v = (i < D_MODEL) ? sh[i] * sc * rmsw[i] : 0.f;
    ubf[(size_t)m * KP_MODEL + i] = __float2bfloat16(v);
  }
}

// last layer: out_proj combine + residual + layernorm + classifier head -> out
__global__ __launch_bounds__(256) void combine_ln(const float* __restrict__ p,
                                                  const float* __restrict__ h,
                                                  const float* __restrict__ lnw,
                                                  const float* __restrict__ lnb,
                                                  const float* __restrict__ ow,
                                                  const float* __restrict__ ob,
                                                  float* __restrict__ out) {
  int row = blockIdx.x;
  __shared__ float sh[D_MODEL];
  __shared__ float red[4];
  int wid = threadIdx.x >> 6, lane = threadIdx.x & 63;
  float s = 0.f;
  for (int i = threadIdx.x; i < D_MODEL; i += 256) {
    size_t ix = (size_t)row * D_MODEL + i;
    float v = h[ix] + p[ix] + p[(size_t)BT * D_MODEL + ix];
    sh[i] = v;
    s += v;
  }
  s = wredx(s);
  if (lane == 0) red[wid] = s;
  __syncthreads();
  float mean = (red[0] + red[1] + red[2] + red[3]) * (1.f / D_MODEL);
  __syncthreads();
  float vs = 0.f;
  for (int i = threadIdx.x; i < D_MODEL; i += 256) { float dd = sh[i] - mean; vs = fmaf(dd, dd, vs); }
  vs = wredx(vs);
  if (lane == 0) red[wid] = vs;
  __syncthreads();
  float var = (red[0] + red[1] + red[2] + red[3]) * (1.f / D_MODEL);
  float inv = rsqrtf(var + 1e-5f);
  for (int i = threadIdx.x; i < D_MODEL; i += 256)
    sh[i] = (sh[i] - mean) * inv * lnw[i] + lnb[i];
  __syncthreads();
  for (int c = wid; c < 10; c += 4) {
    float acc = 0.f;
    for (int i = lane; i < D_MODEL; i += 64) acc = fmaf(sh[i], ow[(size_t)c * D_MODEL + i], acc);
    acc = wredx(acc);
    if (lane == 0) out[(size_t)row * 10 + c] = acc + ob[c];
  }
}

// x_proj combine: parts (2, BT, 256) -> dtbf (BT,64) bf16 + bcbf (BT,64) packed {B,C} bf16x2
__global__ void combine_xproj(const float* __restrict__ p, __hip_bfloat16* __restrict__ dtbf,
                              __hip_bfloat16* __restrict__ bcb) {
  int i = blockIdx.x * 256 + threadIdx.x;
  if (i >= BT * 192) return;
  int m = i / 192, n = i - m * 192;
  if (n >= DT_RANK + 2 * D_STATE) return;
  float v = p[(size_t)m * 256 + n] + p[(size_t)(BT + m) * 256 + n];
  if (n < 64) dtbf[(size_t)m * 64 + n] = __float2bfloat16(n < DT_RANK ? v : 0.f);
  if (n >= DT_RANK && n < DT_RANK + D_STATE)
    bcb[((size_t)m * 64 + (n - DT_RANK)) * 2] = __float2bfloat16(v);          // B -> lo
  else if (n >= DT_RANK + D_STATE)
    bcb[((size_t)m * 64 + (n - DT_RANK - D_STATE)) * 2 + 1] = __float2bfloat16(v);  // C -> hi
}

// ---------------- depthwise causal conv (k=4) + silu -> bf16 only ----------------
__global__ void dwconv_silu(const __hip_bfloat16* __restrict__ xz, const float* __restrict__ cw,
                            const float* __restrict__ cb, __hip_bfloat16* __restrict__ xinbf) {
  int idx = blockIdx.x * 256 + threadIdx.x;
  if (idx >= BT * D_INNER) return;
  int bt = idx / D_INNER;
  int d = idx - bt * D_INNER;
  int t = bt & (T - 1);
  float acc = cb[d];
  const __hip_bfloat16* col = xz + (size_t)bt * D2 + d;
#pragma unroll
  for (int k = 0; k < 4; ++k) {
    int tt = t + k - 3;
    float v = (tt >= 0) ? __bfloat162float(col[(ptrdiff_t)(k - 3) * D2]) : 0.f;
    acc = fmaf(cw[d * 4 + k], v, acc);
  }
  acc = siluf(acc);
  xinbf[(size_t)bt * KP_INNER + d] = __float2bfloat16(acc);
}

// ---------------- fused single-pass scan: 512 threads, 8 waves x 2 d/wave ----------------
// block covers 16 consecutive d for one b; each wave carries TWO independent h chains
// (d = d0+2*wid, d0+2*wid+1) -> 2x ILP on serial fma/exp path, bc loads shared, 4 blocks/CU.
// LDS staging double-buffered per 64-t chunk; reduce: DPP folds + 3 DS ops; slot = brl.

#define FCOMP2(REG, T0L, T0G)                                                \
  {                                                                          \
    float4 qa0 = *(const float4*)&dtsA[(T0L)];                               \
    float4 qa1 = *(const float4*)&dtsA[(T0L) + 4];                           \
    float4 ua0 = *(const float4*)&dtusA[(T0L)];                              \
    float4 ua1 = *(const float4*)&dtusA[(T0L) + 4];                          \
    float4 qb0 = *(const float4*)&dtsB[(T0L)];                               \
    float4 qb1 = *(const float4*)&dtsB[(T0L) + 4];                           \
    float4 ub0 = *(const float4*)&dtusB[(T0L)];                              \
    float4 ub1 = *(const float4*)&dtusB[(T0L) + 4];                          \
    float dtvA[8] = {qa0.x, qa0.y, qa0.z, qa0.w, qa1.x, qa1.y, qa1.z, qa1.w};\
    float duvA[8] = {ua0.x, ua0.y, ua0.z, ua0.w, ua1.x, ua1.y, ua1.z, ua1.w};\
    float dtvB[8] = {qb0.x, qb0.y, qb0.z, qb0.w, qb1.x, qb1.y, qb1.z, qb1.w};\
    float duvB[8] = {ub0.x, ub0.y, ub0.z, ub0.w, ub1.x, ub1.y, ub1.z, ub1.w};\
    float vvA[8], vvB[8];                                                    \
    _Pragma("unroll") for (int k = 0; k < 8; ++k) {                          \
      float Bv = __uint_as_float(REG[k] << 16);                              \
      float Cv = __uint_as_float(REG[k] & 0xffff0000u);                      \
      hA = fmaf(fexp2(dtvA[k] * a2A), hA, duvA[k] * Bv);                     \
      hB = fmaf(fexp2(dtvB[k] * a2B), hB, duvB[k] * Bv);                     \
      vvA[k] = hA * Cv;                                                      \
      vvB[k] = hB * Cv;                                                      \
    }                                                                        \
    _Pragma("unroll") for (int k = 0; k < 4; ++k) {                          \
      float sA = bb0 ? vvA[k] : vvA[k + 4];                                  \
      float kA = bb0 ? vvA[k + 4] : vvA[k];                                  \
      vvA[k] = kA + DPPF(sA, 0xB1);                                          \
      float sB = bb0 ? vvB[k] : vvB[k + 4];                                  \
      float kB = bb0 ? vvB[k + 4] : vvB[k];                                  \
      vvB[k] = kB + DPPF(sB, 0xB1);                                          \
    }                                                                        \
    _Pragma("unroll") for (int k = 0; k < 2; ++k) {                          \
      float sA = bb1 ? vvA[k] : vvA[k + 2];                                  \
      float kA = bb1 ? vvA[k + 2] : vvA[k];                                  \
      vvA[k] = kA + DPPF(sA, 0x4E);                                          \
      float sB = bb1 ? vvB[k] : vvB[k + 2];                                  \
      float kB = bb1 ? vvB[k + 2] : vvB[k];                                  \
      vvB[k] = kB + DPPF(sB, 0x4E);                                          \
    }                                                                        \
    {                                                                        \
      float sA = bb2 ? vvA[0] : vvA[1];                                      \
      float kA = bb2 ? vvA[1] : vvA[0];                                      \
      vvA[0] = kA + SWZF(sA, 0x101F);                                        \
      float sB = bb2 ? vvB[0] : vvB[1];                                      \
      float kB = bb2 ? vvB[1] : vvB[0];                                      \
      vvB[0] = kB + SWZF(sB, 0x101F);                                        \
    }                                                                        \
    float yA = vvA[0], yB = vvB[0];                                          \
    yA += DPPF(yA, 0x128);  yB += DPPF(yB, 0x128);                           \
    yA += SWZF(yA, 0x401F); yB += SWZF(yB, 0x401F);                          \
    yA += __shfl_xor(yA, 32); yB += __shfl_xor(yB, 32);                      \
    if (lane < 8) {                                                          \
      int trow = ((T0L) + brl) * 17;                                         \
      if (vA) {                                                              \
        float yo = (yA + xinS[trow + 2 * wid] * dskA) * siluf(xzS[trow + 2 * wid]); \
        ybf[(rb + (T0G) + brl) * KP_INNER + dA] = __float2bfloat16(yo);      \
      }                                                                      \
      if (vB) {                                                              \
        float yo = (yB + xinS[trow + 2 * wid + 1] * dskB) * siluf(xzS[trow + 2 * wid + 1]); \
        ybf[(rb + (T0G) + brl) * KP_INNER + dB] = __float2bfloat16(yo);      \
      }                                                                      \
    }                                                                        \
  }

__global__ __launch_bounds__(512) void scan_fused(const uint* __restrict__ bcp16,
                                                  const float2* __restrict__ dtdu,
                                                  const __hip_bfloat16* __restrict__ xinbf,
                                                  const __hip_bfloat16* __restrict__ xzbf,
                                                  const float* __restrict__ A_log,
                                                  const float* __restrict__ Dskip,
                                                  __hip_bfloat16* __restrict__ ybf) {
  __shared__ __align__(16) float dts[2][16 * 68];
  __shared__ __align__(16) float dtus[2][16 * 68];
  __shared__ float xins[2][CHT * 17];
  __shared__ float xzs[2][CHT * 17];
  int tid = threadIdx.x, wid = tid >> 6, lane = tid & 63;
  int dg = blockIdx.x % DGRP, b = blockIdx.x / DGRP;
  int d0 = dg * 16;
  int dA = d0 + wid * 2, dB = dA + 1;
  bool vA = (dA < D_INNER), vB = (dB < D_INNER);
  int dcA = vA ? dA : (D_INNER - 1);
  int dcB = vB ? dB : (D_INNER - 1);
  const size_t rb = (size_t)b * T;

  auto stage = [&](int c, int s) {
#pragma unroll
    for (int j = 0; j < 2; ++j) {
      int t2 = tid + j * 512;
      int stt = t2 >> 4, sdd = t2 & 15;
      float2 dq = dtdu[(rb + c * CHT + stt) * D_INNER + d0 + sdd];
      dts[s][sdd * 68 + stt] = dq.x;
      dtus[s][sdd * 68 + stt] = dq.y;
      xins[s][stt * 17 + sdd] = __bfloat162float(xinbf[(rb + c * CHT + stt) * KP_INNER + d0 + sdd]);
      xzs[s][stt * 17 + sdd] = __bfloat162float(xzbf[(rb + c * CHT + stt) * D2 + D_INNER + d0 + sdd]);
    }
  };

  stage(0, 0);

  const bool bb2 = lane & 4, bb1 = lane & 2, bb0 = lane & 1;
  const int brl = ((lane & 1) << 2) | (lane & 2) | ((lane & 4) >> 2);
  float a2A = -__expf(A_log[(size_t)dcA * D_STATE + lane]) * 1.44269504f;
  float a2B = -__expf(A_log[(size_t)dcB * D_STATE + lane]) * 1.44269504f;
  float dskA = Dskip[dcA], dskB = Dskip[dcB];
  float hA = 0.f, hB = 0.f;
  const uint* bgp = bcp16 + rb * 64 + lane;

  __syncthreads();

  uint bA[8], bB[8];
#pragma unroll
  for (int k = 0; k < 8; ++k) bA[k] = bgp[k * 64];

  for (int ch = 0; ch < NCH; ++ch) {
    int s = ch & 1;
    const float* dtsA = &dts[s][(2 * wid) * 68];
    const float* dtusA = &dtus[s][(2 * wid) * 68];
    const float* dtsB = &dts[s][(2 * wid + 1) * 68];
    const float* dtusB = &dtus[s][(2 * wid + 1) * 68];
    const float* xinS = &xins[s][0];
    const float* xzS = &xzs[s][0];
    if (ch + 1 < NCH) stage(ch + 1, s ^ 1);
    const uint* bp = bgp + (size_t)ch * CHT * 64;
#pragma unroll
    for (int gi = 0; gi < 4; ++gi) {
      int t0l = gi * 16;
      int t0g = ch * CHT + t0l;
#pragma unroll
      for (int k = 0; k < 8; ++k) bB[k] = bp[(t0l + 8 + k) * 64];
      FCOMP2(bA, t0l, t0g);
      if (!(ch == NCH - 1 && gi == 3)) {
#pragma unroll
        for (int k = 0; k < 8; ++k) bA[k] = bp[(t0l + 16 + k) * 64];
      }
      FCOMP2(bB, t0l + 8, t0g + 8);
    }
    __syncthreads();
  }
}

// ---------------- launcher ----------------
extern "C" void kernel_launch(void* const* d_in, const int* in_sizes, int n_in,
                              void* d_out, int out_size, void* d_ws, size_t ws_size,
                              hipStream_t stream) {
  const float* x    = (const float*)d_in[0];
  const float* pcw  = (const float*)d_in[1];
  const float* pcb  = (const float*)d_in[2];
  const float* c1w  = (const float*)d_in[3];
  const float* c1b  = (const float*)d_in[4];
  const float* c2w  = (const float*)d_in[5];
  const float* c2b  = (const float*)d_in[6];
  const float* c3w  = (const float*)d_in[7];
  const float* c3b  = (const float*)d_in[8];
  const float* lnw  = (const float*)d_in[9];
  const float* lnb  = (const float*)d_in[10];
  const float* ow   = (const float*)d_in[11];
  const float* ob   = (const float*)d_in[12];
  const float* rmsw = (const float*)d_in[13];
  const float* Wi   = (const float*)d_in[14];
  const float* dww  = (const float*)d_in[15];
  const float* dwb  = (const float*)d_in[16];
  const float* Wx   = (const float*)d_in[17];
  const float* Wdt  = (const float*)d_in[18];
  const float* dtbv = (const float*)d_in[19];
  const float* Alog = (const float*)d_in[20];
  const float* Dsk  = (const float*)d_in[21];
  const float* Wo   = (const float*)d_in[22];
  float* out = (float*)d_out;

  char* w = (char*)d_ws;
  auto alloc = [&](size_t n) { char* p = w; w += (n + 255) & ~(size_t)255; return p; };
  // shared region: front-end buffers (dead after front GEMM) aliased with scan temps
  constexpr size_t REGION = 26400000;
  char* region = alloc(REGION);
  __hip_bfloat16* hpbf = (__hip_bfloat16*)region;                    // 524,288 B
  __hip_bfloat16* Xim  = (__hip_bfloat16*)(region + 600064);         // 14,155,776 B
  __hip_bfloat16* Wfr  = (__hip_bfloat16*)(region + 14755840 + 256); // 5,308,416 B
  float* cb768         = (float*)(region + 20065024);                // 3,072 B
  float2* dtduT        = (float2*)region;                            // 25,198,592 B (layer phase)
  __hip_bfloat16* bcbf = (__hip_bfloat16*)(region + 25198592);       // 524,288 B packed {B,C}

  float* hbuf          = (float*)alloc((size_t)BT * D_MODEL * 4);
  __hip_bfloat16* ubf  = (__hip_bfloat16*)alloc((size_t)BT * KP_MODEL * 2);
  __hip_bfloat16* xzbf = (__hip_bfloat16*)alloc((size_t)BT * D2 * 2);
  __hip_bfloat16* xinbf= (__hip_bfloat16*)alloc((size_t)BT * KP_INNER * 2);
  __hip_bfloat16* dtbf = (__hip_bfloat16*)alloc((size_t)BT * KP_DT * 2);
  __hip_bfloat16* ybf  = (__hip_bfloat16*)alloc((size_t)BT * KP_INNER * 2);
  __hip_bfloat16* Wibf = (__hip_bfloat16*)alloc((size_t)2 * NP_IN * KP_MODEL * 2);
  __hip_bfloat16* Wxbf = (__hip_bfloat16*)alloc((size_t)2 * NP_X * KP_INNER * 2);
  __hip_bfloat16* Wdtbf= (__hip_bfloat16*)alloc((size_t)2 * NP_DT * KP_DT * 2);
  __hip_bfloat16* Wobf = (__hip_bfloat16*)alloc((size_t)2 * NP_OUT * KP_INNER * 2);
  float* parts         = (float*)alloc((size_t)2 * BT * D_MODEL * 4);          // 12.6 MB split-K partials

  front_pointconv<<<dim3(T, B), 128, 0, stream>>>(x, pcw, pcb, hpbf);
  im2col_front<<<(BT * 432) / 256, 256, 0, stream>>>(hpbf, Xim);
  build_conv_wb<<<2048, 256, 0, stream>>>(c1w, c2w, c3w, c1b, c2b, c3b, Wfr, cb768);
  cvt_all<<<dim3(1024, 8), 256, 0, stream>>>(Wi, Wx, Wdt, Wo, Wibf, Wxbf, Wdtbf, Wobf);
  gemm_bf16<6><<<dim3(NCONV / 128, BT / 128, 2), 256, 0, stream>>>(Xim, Wfr, parts, BT, NCONV, KCONV,
                                                                   nullptr, 0, NCONV,
                                                                   nullptr, nullptr, nullptr);
  combine_conv_rms<<<BT, 256, 0, stream>>>(parts, cb768, x, rmsw, hbuf, ubf);
  // pad columns written once (scan/dwconv never touch cols >= D_INNER)
  zero_pad_cols<<<(BT * (KP_INNER - D_INNER) + 255) / 256, 256, 0, stream>>>(xinbf, BT, KP_INNER, D_INNER);
  zero_pad_cols<<<(BT * (KP_INNER - D_INNER) + 255) / 256, 256, 0, stream>>>(ybf, BT, KP_INNER, D_INNER);

  for (int l = 0; l < 2; ++l) {
    const float* Al = Alog + (size_t)l * D_INNER * D_STATE;
    gemm_bf16<7><<<dim3(NP_IN / 128, BT / 128), 256, 0, stream>>>(
        ubf, Wibf + (size_t)l * NP_IN * KP_MODEL, nullptr, BT, D2, KP_MODEL,
        nullptr, 0, D2, nullptr, xzbf, nullptr);
    dwconv_silu<<<(BT * D_INNER + 255) / 256, 256, 0, stream>>>(xzbf, dww + (size_t)l * D_INNER * 4,
                                                                dwb + (size_t)l * D_INNER, xinbf);
    gemm_bf16<6><<<dim3(NP_X / 128, BT / 128, 2), 256, 0, stream>>>(
        xinbf, Wxbf + (size_t)l * NP_X * KP_INNER, parts, BT,
        DT_RANK + 2 * D_STATE, KP_INNER, nullptr, 0, 256, nullptr, nullptr, nullptr);
    combine_xproj<<<(BT * 192 + 255) / 256, 256, 0, stream>>>(parts, dtbf, bcbf);
    gemm_bf16<1><<<dim3(NP_DT / 128, BT / 128), 256, 0, stream>>>(
        dtbf, Wdtbf + (size_t)l * NP_DT * KP_DT, nullptr, BT, D_INNER, KP_DT,
        dtbv + (size_t)l * D_INNER, 0, 0, dtduT, nullptr, xinbf);
    scan_fused<<<dim3(B * DGRP), 512, 0, stream>>>((const uint*)bcbf, dtduT, xinbf, xzbf, Al,
                                                   Dsk + (size_t)l * D_INNER, ybf);
    gemm_bf16<6><<<dim3(NP_OUT / 128, BT / 128, 2), 256, 0, stream>>>(
        ybf, Wobf + (size_t)l * NP_OUT * KP_INNER, parts, BT, D_MODEL, KP_INNER,
        nullptr, 0, D_MODEL, nullptr, nullptr, nullptr);
    if (l == 0) {
      combine_out_rms<<<BT, 256, 0, stream>>>(parts, rmsw + D_MODEL, hbuf, ubf);
    } else {
      combine_ln<<<BT, 256, 0, stream>>>(parts, hbuf, lnw, lnb, ow, ob, out);
    }
  }
}